// Round 1
// baseline (4742.765 us; speedup 1.0000x reference)
//
#include <hip/hip_runtime.h>

#define MM 2048
#define NN 2048
#define DD 64
#define NDIAG (MM + NN - 1)      /* 4095 cost-matrix anti-diagonals */
#define TOTCELLS (MM * NN)
#define MAXSEG 15

constexpr float F_INF = 1e10f;
constexpr float K2    = 14.426950408889634f;   // log2(e)/gamma, gamma=0.1
constexpr float GLN2  = 0.06931471805599453f;  // gamma*ln2
constexpr float INV_G = 10.0f;                 // 1/gamma
constexpr float LOG2E = 1.4426950408889634f;

// Packed anti-diagonal layout for a 2048x2048 matrix: diag d = i+j, 0..4094.
__device__ __forceinline__ int diag_off(int d) {
    return (d < NN) ? ((d * (d + 1)) >> 1)
                    : (TOTCELLS - (((NDIAG - d) * (NDIAG - d + 1)) >> 1));
}
__device__ __forceinline__ int diag_imin(int d) { return (d < NN) ? 0 : (d - (NN - 1)); }
__device__ __forceinline__ int diag_len(int d)  { return (d < NN) ? (d + 1) : (NDIAG - d); }

__device__ __forceinline__ float fexp2(float x) { return __builtin_amdgcn_exp2f(x); }
__device__ __forceinline__ float flog2(float x) { return __builtin_amdgcn_logf(x); }

// -gamma*logsumexp(-x/gamma) over {a,b,c}; stable: s=min, Sum in [1,3].
__device__ __forceinline__ float softmin3(float a, float b, float c) {
    float s = fminf(fminf(a, b), c);
    float e = fexp2((s - a) * K2) + fexp2((s - b) * K2) + fexp2((s - c) * K2);
    return s - GLN2 * flog2(e);
}

// ---------------------------------------------------------------------------
// cost[i,j] = sum_k (target[i,k]-pred[j,k])^2, written in packed diag layout.
// 64x64 tile per 256-thread block; pred tile stored k-major (padded) so the
// inner loop is bank-conflict-free. Block (0,0) also zeroes the accumulators.
// ---------------------------------------------------------------------------
__global__ __launch_bounds__(256) void cost_kernel(const float* __restrict__ pred,
                                                   const float* __restrict__ target,
                                                   float* __restrict__ costD,
                                                   float* __restrict__ acc) {
    __shared__ float Ts[64][65];   // Ts[r][k]  = target[(i0+r)*64+k]
    __shared__ float Ps[64][65];   // Ps[k][c]  = pred  [(j0+c)*64+k]  (transposed)
    const int tid = threadIdx.x;
    const int tx = tid & 15, ty = tid >> 4;
    const int i0 = blockIdx.y * 64;
    const int j0 = blockIdx.x * 64;

    if (blockIdx.x == 0 && blockIdx.y == 0 && tid < 64) acc[tid] = 0.0f;

    #pragma unroll
    for (int rnd = 0; rnd < 4; ++rnd) {
        int f4i = tid + rnd * 256;
        int r  = f4i >> 4;
        int k4 = (f4i & 15) << 2;
        float4 tv = *reinterpret_cast<const float4*>(target + (size_t)(i0 + r) * DD + k4);
        Ts[r][k4 + 0] = tv.x; Ts[r][k4 + 1] = tv.y; Ts[r][k4 + 2] = tv.z; Ts[r][k4 + 3] = tv.w;
        float4 pv = *reinterpret_cast<const float4*>(pred + (size_t)(j0 + r) * DD + k4);
        Ps[k4 + 0][r] = pv.x; Ps[k4 + 1][r] = pv.y; Ps[k4 + 2][r] = pv.z; Ps[k4 + 3][r] = pv.w;
    }
    __syncthreads();

    float accv[4][4];
    #pragma unroll
    for (int a = 0; a < 4; ++a)
        #pragma unroll
        for (int b = 0; b < 4; ++b) accv[a][b] = 0.f;

    for (int k = 0; k < 64; ++k) {
        float ta[4], pb[4];
        #pragma unroll
        for (int a = 0; a < 4; ++a) ta[a] = Ts[ty + 16 * a][k];
        #pragma unroll
        for (int b = 0; b < 4; ++b) pb[b] = Ps[k][tx + 16 * b];
        #pragma unroll
        for (int a = 0; a < 4; ++a)
            #pragma unroll
            for (int b = 0; b < 4; ++b) {
                float d = ta[a] - pb[b];
                accv[a][b] = fmaf(d, d, accv[a][b]);
            }
    }
    #pragma unroll
    for (int a = 0; a < 4; ++a) {
        int i = i0 + ty + 16 * a;
        #pragma unroll
        for (int b = 0; b < 4; ++b) {
            int j = j0 + tx + 16 * b;
            int d = i + j;
            costD[diag_off(d) + (i - diag_imin(d))] = accv[a][b];
        }
    }
}

// ---------------------------------------------------------------------------
// Soft-DTW forward (block 0) and backward (block 1), run concurrently.
// LDS ring of 3 diagonals indexed by absolute row; 1 barrier per diagonal.
// ---------------------------------------------------------------------------
__global__ __launch_bounds__(1024) void dp_kernel(const float* __restrict__ costD,
                                                  float* __restrict__ fwdD,
                                                  float* __restrict__ bwdD) {
    __shared__ float ring[3][MM + 2];
    const int tid = threadIdx.x;

    if (blockIdx.x == 0) {
        // ---------------- forward: R[i,j] = c + softmin(diag, up, left) -----
        for (int r = tid; r <= MM + 1; r += 1024) {
            ring[0][r] = (r == 0) ? 0.f : F_INF;  // diag i+j=0 : R[0,0]=0
            ring[1][r] = F_INF;                   // diag i+j=1 : all INF
            ring[2][r] = F_INF;
        }
        __syncthreads();
        int zm2 = 0, zm1 = 1, znew = 2;
        for (int t = 0; t < NDIAG; ++t) {          // cost diag t; R-diag dR=t+2
            const int ofs = diag_off(t), imin = diag_imin(t), len = diag_len(t);
            float* __restrict__ Dm2 = ring[zm2];
            float* __restrict__ Dm1 = ring[zm1];
            float* __restrict__ Dn  = ring[znew];
            #pragma unroll
            for (int h = 0; h < 2; ++h) {
                const int r = tid + 1 + h * 1024;   // row i = 1..2048
                const int x = r - 1 - imin;
                float v = F_INF;
                if (x >= 0 && x < len) {
                    float c = costD[ofs + x];
                    v = c + softmin3(Dm2[r - 1], Dm1[r - 1], Dm1[r]);
                    fwdD[ofs + x] = v;
                }
                Dn[r] = v;
            }
            if (tid == 0) Dn[0] = F_INF;
            __syncthreads();
            int z = zm2; zm2 = zm1; zm1 = znew; znew = z;
        }
    } else {
        // ---------------- backward: E[i,j]=softmin(E[i+1,j+1]+c(i,j),
        //                   E[i+1,j]+c(i,j-1), E[i,j+1]+c(i-1,j)) ------------
        for (int r = tid; r <= MM + 1; r += 1024) {
            ring[0][r] = (r == MM) ? 0.f : F_INF; // diag i+j=m+n : E[m,n]=0
            ring[1][r] = F_INF;                   // diag m+n+1 : all INF
            ring[2][r] = F_INF;
        }
        if (tid == 0) bwdD[TOTCELLS - 1] = 0.f;   // b at (m,n) is 0 per reference
        __syncthreads();
        int zp1 = 0, zp2 = 1, znew = 2;
        for (int t = 0; t < NDIAG - 1; ++t) {
            const int dR = NDIAG - t;              // R-diag 4095 .. 2
            const int d0 = dR - 2;                 // output cost-diag
            const int ofs0 = diag_off(d0), imin0 = diag_imin(d0);
            const int ofsA = diag_off(dR),     iminA = diag_imin(dR);      // c(i,j)
            const int ofsB = diag_off(dR - 1), iminB = diag_imin(dR - 1);  // c(i,j-1), c(i-1,j)
            float* __restrict__ Ep1 = ring[zp1];
            float* __restrict__ Ep2 = ring[zp2];
            float* __restrict__ En  = ring[znew];
            #pragma unroll
            for (int h = 0; h < 2; ++h) {
                const int i = tid + 1 + h * 1024;  // row i = 1..2048 (1-indexed)
                const int j = dR - i;
                float v = F_INF;
                if (j >= 1 && j <= NN) {
                    float dc = F_INF, bc = F_INF, rc = F_INF;
                    if (i < MM && j < NN) dc = Ep2[i + 1] + costD[ofsA + (i     - iminA)];
                    if (i < MM)           bc = Ep1[i + 1] + costD[ofsB + (i     - iminB)];
                    if (j < NN)           rc = Ep1[i]     + costD[ofsB + (i - 1 - iminB)];
                    v = softmin3(dc, bc, rc);
                    bwdD[ofs0 + (i - 1 - imin0)] = v;
                }
                En[i] = v;
            }
            if (tid == 0) { En[0] = F_INF; En[MM + 1] = F_INF; }
            __syncthreads();
            int z = zp2; zp2 = zp1; zp1 = znew; znew = z;
        }
    }
}

// ---------------------------------------------------------------------------
// Per-cell alignment + linear reductions. One block per diagonal (coalesced).
// acc layout: [0]=total [1]=temporal [2]=boundary [3..3+14]=seg mass
//             [18..32]=seg mass*j_pos
// ---------------------------------------------------------------------------
__device__ __forceinline__ float wave_red(float v) {
    v += __shfl_xor(v, 32, 64);
    v += __shfl_xor(v, 16, 64);
    v += __shfl_xor(v, 8, 64);
    v += __shfl_xor(v, 4, 64);
    v += __shfl_xor(v, 2, 64);
    v += __shfl_xor(v, 1, 64);
    return v;
}

__global__ __launch_bounds__(256) void combine_kernel(const float* __restrict__ costD,
                                                      const float* __restrict__ fwdD,
                                                      const float* __restrict__ bwdD,
                                                      const int* __restrict__ gbp, int ngb,
                                                      float* __restrict__ acc) {
    const int d = blockIdx.x;
    const int ofs = diag_off(d), imin = diag_imin(d), len = diag_len(d);
    const float dist = fwdD[TOTCELLS - 1];
    __shared__ float sseg[MAXSEG], ssegp[MAXSEG];
    __shared__ int sgb[MAXSEG + 1];
    const int tid = threadIdx.x;
    if (tid < MAXSEG) { sseg[tid] = 0.f; ssegp[tid] = 0.f; }
    if (tid < ngb && tid <= MAXSEG) sgb[tid] = gbp[tid];
    __syncthreads();

    float pT = 0.f, pTe = 0.f, pB = 0.f;
    const float invM1 = 1.f / (float)(MM - 1);
    const float invN1 = 1.f / (float)(NN - 1);
    const int nseg = ngb - 1;

    for (int x = tid; x < len; x += 256) {
        const int i0 = imin + x, j0 = d - i0;
        const float f = fwdD[ofs + x], b = bwdD[ofs + x], c = costD[ofs + x];
        // reference: log_prob = min(-(f+c+b-dist)/g, 0); a = exp(log_prob)
        const float lp = fminf(-(f + c + b - dist) * INV_G, 0.f);
        const float a = fexp2(lp * LOG2E);
        const float jp = j0 * invN1, ip = i0 * invM1;
        pT += a;
        const float dt = ip - jp;
        pTe += a * dt * dt;
        int s = -1;
        for (int q = 0; q < nseg && q < MAXSEG; ++q)
            if (i0 >= sgb[q] && i0 < sgb[q + 1]) s = q;
        if (s >= 0) { atomicAdd(&sseg[s], a); atomicAdd(&ssegp[s], a * jp); }
        for (int q = 0; q < ngb && q <= MAXSEG; ++q) {
            const int bv = sgb[q];
            if (bv > 0 && bv < MM && i0 == bv) {
                const float dv = jp - (float)bv * invM1;
                pB += a * dv * dv;
            }
        }
    }
    pT = wave_red(pT); pTe = wave_red(pTe); pB = wave_red(pB);
    if ((tid & 63) == 0) {
        if (pT  != 0.f) atomicAdd(&acc[0], pT);
        if (pTe != 0.f) atomicAdd(&acc[1], pTe);
        if (pB  != 0.f) atomicAdd(&acc[2], pB);
    }
    __syncthreads();
    if (tid < nseg && tid < MAXSEG) {
        if (sseg[tid]  != 0.f) atomicAdd(&acc[3 + tid], sseg[tid]);
        if (ssegp[tid] != 0.f) atomicAdd(&acc[3 + MAXSEG + tid], ssegp[tid]);
    }
}

// ---------------------------------------------------------------------------
// Scalar epilogue replicating the reference's scale/order/coverage semantics.
// ---------------------------------------------------------------------------
__global__ void final_kernel(const float* __restrict__ acc,
                             const float* __restrict__ fwdD,
                             const int* __restrict__ gbp, int ngb,
                             float* __restrict__ out) {
    if (threadIdx.x != 0 || blockIdx.x != 0) return;
    const float dist = fwdD[TOTCELLS - 1];
    const float Utot = acc[0];
    const float scale = (Utot > 1e-8f) ? ((float)(MM < NN ? MM : NN) / fmaxf(Utot, 1e-8f)) : 1.0f;
    const float temporal = scale * acc[1];

    int gb[MAXSEG + 1];
    const int n = (ngb <= MAXSEG + 1) ? ngb : (MAXSEG + 1);
    for (int q = 0; q < n; ++q) gb[q] = gbp[q];

    int nint = 0;
    for (int q = 0; q < n; ++q) if (gb[q] > 0 && gb[q] < MM) nint++;
    const float boundary = (nint > 0) ? (scale * acc[2] / (float)nint) : 0.f;

    float order = 0.f;
    if (n > 2) {
        float pos[MAXSEG];
        int np = 0;
        for (int s = 0; s + 1 < n; ++s) {
            const int st = gb[s], en = gb[s + 1];
            if (st >= MM || en > MM || st >= en) continue;
            const float mass = fmaxf(scale * acc[3 + s], 1e-8f);
            pos[np++] = scale * acc[3 + MAXSEG + s] / mass;
        }
        for (int k = 1; k < np; ++k) order += fmaxf(pos[k - 1] - pos[k], 0.f);
        if (np > 1) order /= (float)(np - 1);
    }

    float cov = 0.f;
    const int nsteps = n - 1;
    if (nsteps > 0) {
        for (int s = 0; s < nsteps; ++s) {
            const int st = gb[s];
            int en = gb[s + 1]; if (en > MM) en = MM;
            if (st >= en) continue;
            cov += fmaxf((float)(en - st) * 0.5f - scale * acc[3 + s], 0.f);
        }
        cov /= (float)nsteps;
    }

    out[0] = 0.3f * dist + 0.2f * temporal + 0.2f * boundary + 0.15f * order + 0.15f * cov;
}

// ---------------------------------------------------------------------------
extern "C" void kernel_launch(void* const* d_in, const int* in_sizes, int n_in,
                              void* d_out, int out_size, void* d_ws, size_t ws_size,
                              hipStream_t stream) {
    const float* pred   = (const float*)d_in[0];   // (2048, 64)
    const float* target = (const float*)d_in[1];   // (2048, 64)
    const int*   gb     = (const int*)d_in[2];     // (9,)
    const int ngb = in_sizes[2];

    float* costD = (float*)d_ws;
    float* fwdD  = costD + TOTCELLS;
    float* bwdD  = fwdD + TOTCELLS;
    float* acc   = bwdD + TOTCELLS;   // 64 floats, zeroed by cost_kernel block (0,0)

    cost_kernel<<<dim3(NN / 64, MM / 64), 256, 0, stream>>>(pred, target, costD, acc);
    dp_kernel<<<2, 1024, 0, stream>>>(costD, fwdD, bwdD);
    combine_kernel<<<NDIAG, 256, 0, stream>>>(costD, fwdD, bwdD, gb, ngb, acc);
    final_kernel<<<1, 64, 0, stream>>>(acc, fwdD, gb, ngb, (float*)d_out);
}

// Round 2
// 3765.547 us; speedup vs baseline: 1.2595x; 1.2595x over previous
//
#include <hip/hip_runtime.h>

#define MM 2048
#define NN 2048
#define DD 64
#define NDIAG (MM + NN - 1)      /* 4095 cost-matrix anti-diagonals */
#define TOTCELLS (MM * NN)
#define MAXSEG 15

// ---- skewed-pipeline DP geometry ----
#define NWGD   4                 /* workgroups per direction            */
#define NWAVE  4                 /* waves per WG                        */
#define STRIPROWS 128            /* rows per wave (2 per lane)          */
#define ASKEW  160               /* time-shift between adjacent strips  */
#define KSTEP  32                /* steps per super-step (barrier cad.) */
#define TSTEPS 4608              /* >= 2047 + 15*ASKEW + 127 + 1 = 4575 */
#define NSUPER (TSTEPS / KSTEP)
#define GRING  1024              /* global ring entries per boundary    */
#define LRING  256               /* LDS ring entries per boundary       */

constexpr float K2      = 14.426950408889634f;   // log2(e)/gamma, gamma=0.1
constexpr float INF_K   = 1.0e10f * 14.426950408889634f;
constexpr float UNSCALE = 0.06931471805599453f;  // gamma*ln2 = 1/K2

// Packed anti-diagonal layout for a 2048x2048 matrix: diag d = i+j, 0..4094.
__device__ __forceinline__ int diag_off(int d) {
    return (d < NN) ? ((d * (d + 1)) >> 1)
                    : (TOTCELLS - (((NDIAG - d) * (NDIAG - d + 1)) >> 1));
}
__device__ __forceinline__ int diag_imin(int d) { return (d < NN) ? 0 : (d - (NN - 1)); }
__device__ __forceinline__ int diag_len(int d)  { return (d < NN) ? (d + 1) : (NDIAG - d); }

__device__ __forceinline__ float fexp2(float x) { return __builtin_amdgcn_exp2f(x); }
__device__ __forceinline__ float flog2(float x) { return __builtin_amdgcn_logf(x); }

// softmin in the K2-scaled (log2) domain: -g*lse(-x/g) scaled by K2 becomes
// m1 - log2(1 + 2^(m1-m2) + 2^(m1-m3)),  m1<=m2<=m3 sorted inputs.
__device__ __forceinline__ float softmin3k(float a, float b, float c) {
    const float m1 = fminf(fminf(a, b), c);
    const float m2 = __builtin_amdgcn_fmed3f(a, b, c);
    const float m3 = fmaxf(fmaxf(a, b), c);
    const float e  = 1.0f + fexp2(m1 - m2) + fexp2(m1 - m3);
    return m1 - flog2(e);
}

// ---------------------------------------------------------------------------
// cost[i,j] = K2 * sum_k (target[i,k]-pred[j,k])^2, packed diag layout.
// Block (0,0) also zeroes accumulators + pipeline flags (80 words).
// ---------------------------------------------------------------------------
__global__ __launch_bounds__(256) void cost_kernel(const float* __restrict__ pred,
                                                   const float* __restrict__ target,
                                                   float* __restrict__ costD,
                                                   float* __restrict__ acc) {
    __shared__ float Ts[64][65];
    __shared__ float Ps[64][65];
    const int tid = threadIdx.x;
    const int tx = tid & 15, ty = tid >> 4;
    const int i0 = blockIdx.y * 64;
    const int j0 = blockIdx.x * 64;

    if (blockIdx.x == 0 && blockIdx.y == 0 && tid < 80) ((unsigned*)acc)[tid] = 0u;

    #pragma unroll
    for (int rnd = 0; rnd < 4; ++rnd) {
        int f4i = tid + rnd * 256;
        int r  = f4i >> 4;
        int k4 = (f4i & 15) << 2;
        float4 tv = *reinterpret_cast<const float4*>(target + (size_t)(i0 + r) * DD + k4);
        Ts[r][k4 + 0] = tv.x; Ts[r][k4 + 1] = tv.y; Ts[r][k4 + 2] = tv.z; Ts[r][k4 + 3] = tv.w;
        float4 pv = *reinterpret_cast<const float4*>(pred + (size_t)(j0 + r) * DD + k4);
        Ps[k4 + 0][r] = pv.x; Ps[k4 + 1][r] = pv.y; Ps[k4 + 2][r] = pv.z; Ps[k4 + 3][r] = pv.w;
    }
    __syncthreads();

    float accv[4][4];
    #pragma unroll
    for (int a = 0; a < 4; ++a)
        #pragma unroll
        for (int b = 0; b < 4; ++b) accv[a][b] = 0.f;

    for (int k = 0; k < 64; ++k) {
        float ta[4], pb[4];
        #pragma unroll
        for (int a = 0; a < 4; ++a) ta[a] = Ts[ty + 16 * a][k];
        #pragma unroll
        for (int b = 0; b < 4; ++b) pb[b] = Ps[k][tx + 16 * b];
        #pragma unroll
        for (int a = 0; a < 4; ++a)
            #pragma unroll
            for (int b = 0; b < 4; ++b) {
                float d = ta[a] - pb[b];
                accv[a][b] = fmaf(d, d, accv[a][b]);
            }
    }
    #pragma unroll
    for (int a = 0; a < 4; ++a) {
        int i = i0 + ty + 16 * a;
        #pragma unroll
        for (int b = 0; b < 4; ++b) {
            int j = j0 + tx + 16 * b;
            int d = i + j;
            costD[diag_off(d) + (i - diag_imin(d))] = accv[a][b] * K2;
        }
    }
}

// ---------------------------------------------------------------------------
// Skewed register-resident soft-DTW. blocks 0-3: forward -> fwdD (scaled R).
// blocks 4-7: backward as forward on 180-rotated cost -> bwdD (scaled B=b+c).
// Lane i of strip g owns rows 128g+2i, 128g+2i+1; at wall-step t it computes
// both cells on diagonal dd = t - 32g (cols dd-r0, dd-r0-1). All deps are
// previous-step registers: left/up/diag via own regs + one rotate-shuffle.
// Strip boundaries: LDS ring (intra-WG, lag 33 > KSTEP) / global ring with
// agent-scope atomics + progress flags (inter-WG, polled per super-step).
// ---------------------------------------------------------------------------
__global__ __launch_bounds__(256) void dp_pipe(const float* __restrict__ costD,
                                               float* __restrict__ fwdD,
                                               float* __restrict__ bwdD,
                                               unsigned* __restrict__ flagsP,
                                               unsigned* __restrict__ cprogP,
                                               float* __restrict__ gringP) {
    __shared__ float ring[NWAVE][LRING];
    const int dir  = (int)blockIdx.x >> 2;
    const int wg   = (int)blockIdx.x & 3;
    const int tid  = threadIdx.x;
    const int wv   = tid >> 6;
    const int lane = tid & 63;
    const int g    = wg * NWAVE + wv;       // strip id 0..15
    const int S    = ASKEW * g;             // wall-clock shift of this strip
    const int r0   = STRIPROWS * g + 2 * lane;
    float* __restrict__ outD = dir ? bwdD : fwdD;
    unsigned* pf = flagsP + dir * NWGD;
    unsigned* cf = cprogP + dir * NWGD;
    float* grd   = gringP + dir * 3 * GRING;
    const int shl = (lane + 63) & 63;       // rotate-up-by-1 source lane

    float Rk0 = INF_K, Rk0m1 = INF_K, Rk1 = INF_K;
    float dg0 = (g == 0 && lane == 0) ? 0.0f : INF_K;  // virtual R[0][0]=0
    float extP = INF_K;                      // gathered inter-WG boundary vals
    float ccA0 = 0.f, ccA1 = 0.f, ccB0 = 0.f, ccB1 = 0.f;

    // prologue: prefetch cost for t=0 (only strip 0 is active at t=0; dd=0)
    if (g == 0) {
        int a0 = (dir == 0) ? r0 : ((MM - 1) - r0);
        int a1 = (dir == 0) ? (a0 + 1) : (a0 - 1);
        ccA0 = costD[a0]; ccA1 = costD[a1];
    }

    auto STEP = [&](int t, float& cc0, float& cc1, float& nc0, float& nc1) {
        const int dd = t - KSTEP * g;        // diagonal this strip works on
        // prefetch cost for step t+1
        const int ddn = dd + 1;
        if (ddn >= 0 && ddn <= NDIAG - 1) {
            const int off = diag_off(ddn), im = diag_imin(ddn);
            const int a0 = (dir == 0) ? (off - im + r0) : (off + (MM - 1) - im - r0);
            const int a1 = (dir == 0) ? (a0 + 1) : (a0 - 1);
            nc0 = costD[a0]; nc1 = costD[a1];
        }
        if (dd >= 0 && dd <= NDIAG - 1) {
            const int c0 = dd - r0;          // column of the r0 cell
            // boundary value for lane 0 (row r0-1 of previous strip, col c0)
            float ext;
            if (wv == 0) {
                ext = (wg == 0) ? INF_K : __shfl(extP, t & (KSTEP - 1), 64);
            } else {
                const int ec = t - S;
                const float rv = ring[wv - 1][ec & (LRING - 1)];
                ext = (ec >= 0 && ec < NN) ? rv : INF_K;
            }
            const float shr = __shfl(Rk1, shl, 64);     // neighbor lane's row r0-1
            const float up0 = (lane == 0) ? ext : shr;
            const float n0 = cc0 + softmin3k(dg0, up0, Rk0);
            const float n1 = cc1 + softmin3k(Rk0m1, Rk0, Rk1);
            const bool v0 = (c0 >= 0) && (c0 < NN);
            const bool v1 = (c0 >= 1) && (c0 <= NN);    // col c0-1 valid
            Rk0m1 = Rk0;
            if (v0) Rk0 = n0;
            if (v1) Rk1 = n1;
            dg0 = up0;
            const int off = diag_off(dd), im = diag_imin(dd);
            const int a0 = (dir == 0) ? (off - im + r0) : (off + (MM - 1) - im - r0);
            const int a1 = (dir == 0) ? (a0 + 1) : (a0 - 1);
            if (v0) outD[a0] = Rk0;
            if (v1) outD[a1] = Rk1;
            // publish strip's last row (lane 63, second row) to the LDS ring
            const int pc = t - S - (STRIPROWS - 1);
            if (lane == 63 && pc >= 0 && pc < NN) ring[wv][pc & (LRING - 1)] = Rk1;
        }
    };

    for (unsigned m = 0; m < NSUPER; ++m) {
        // inter-WG consumer: spin for producer flag, gather ring values
        if (wv == 0 && wg > 0) {
            const int c0g = (int)(m * KSTEP) - S;
            if (c0g + KSTEP - 1 >= 0 && c0g <= NN - 1) {
                unsigned guard = 0;
                while (__hip_atomic_load(&pf[wg - 1], __ATOMIC_ACQUIRE,
                                         __HIP_MEMORY_SCOPE_AGENT) < m &&
                       guard < (1u << 24)) { __builtin_amdgcn_s_sleep(2); ++guard; }
                const int c = c0g + lane;
                float v = INF_K;
                if (c >= 0 && c < NN)
                    v = __hip_atomic_load(&grd[(wg - 1) * GRING + (c & (GRING - 1))],
                                          __ATOMIC_RELAXED, __HIP_MEMORY_SCOPE_AGENT);
                extP = v;
            } else {
                extP = INF_K;
            }
        }

        const int tbase = (int)(m * KSTEP);
        for (int tt = 0; tt < KSTEP; tt += 2) {
            STEP(tbase + tt,     ccA0, ccA1, ccB0, ccB1);
            STEP(tbase + tt + 1, ccB0, ccB1, ccA0, ccA1);
        }
        __syncthreads();

        // inter-WG producer: flush wave-3 ring segment to global + flag
        if (wv == 0 && wg < NWGD - 1) {
            if (lane == 0) {   // back-pressure vs slow consumer (ring wrap)
                unsigned guard = 0;
                while ((int)m - (int)__hip_atomic_load(&cf[wg + 1], __ATOMIC_RELAXED,
                                                       __HIP_MEMORY_SCOPE_AGENT) > 24 &&
                       guard < (1u << 24)) { __builtin_amdgcn_s_sleep(2); ++guard; }
            }
            const int Sp = ASKEW * (wg * NWAVE + (NWAVE - 1));
            const int cb = (int)(m * KSTEP) - Sp - (STRIPROWS - 1);
            if (lane < KSTEP) {
                const int c = cb + lane;
                if (c >= 0 && c < NN) {
                    float v = ring[NWAVE - 1][c & (LRING - 1)];
                    __hip_atomic_store(&grd[wg * GRING + (c & (GRING - 1))], v,
                                       __ATOMIC_RELAXED, __HIP_MEMORY_SCOPE_AGENT);
                }
            }
            if (lane == 0)
                __hip_atomic_store(&pf[wg], m + 1, __ATOMIC_RELEASE,
                                   __HIP_MEMORY_SCOPE_AGENT);
        }
        if (wg > 0 && tid == 0)
            __hip_atomic_store(&cf[wg], m + 1, __ATOMIC_RELAXED,
                               __HIP_MEMORY_SCOPE_AGENT);
    }
}

// ---------------------------------------------------------------------------
// Per-cell alignment + linear reductions. a = exp2(-max(f + B - dist, 0)).
// acc: [0]=total [1]=temporal [2]=boundary [3..17]=seg mass [18..32]=seg pos
// ---------------------------------------------------------------------------
__device__ __forceinline__ float wave_red(float v) {
    v += __shfl_xor(v, 32, 64);
    v += __shfl_xor(v, 16, 64);
    v += __shfl_xor(v, 8, 64);
    v += __shfl_xor(v, 4, 64);
    v += __shfl_xor(v, 2, 64);
    v += __shfl_xor(v, 1, 64);
    return v;
}

__global__ __launch_bounds__(256) void combine_kernel(const float* __restrict__ fwdD,
                                                      const float* __restrict__ bwdD,
                                                      const int* __restrict__ gbp, int ngb,
                                                      float* __restrict__ acc) {
    const int d = blockIdx.x;
    const int ofs = diag_off(d), imin = diag_imin(d), len = diag_len(d);
    const float dist = fwdD[TOTCELLS - 1];
    __shared__ float sseg[MAXSEG], ssegp[MAXSEG];
    __shared__ int sgb[MAXSEG + 1];
    const int tid = threadIdx.x;
    if (tid < MAXSEG) { sseg[tid] = 0.f; ssegp[tid] = 0.f; }
    if (tid < ngb && tid <= MAXSEG) sgb[tid] = gbp[tid];
    __syncthreads();

    float pT = 0.f, pTe = 0.f, pB = 0.f;
    const float invM1 = 1.f / (float)(MM - 1);
    const float invN1 = 1.f / (float)(NN - 1);
    const int nseg = ngb - 1;

    for (int x = tid; x < len; x += 256) {
        const int i0 = imin + x, j0 = d - i0;
        const float f = fwdD[ofs + x], b = bwdD[ofs + x];
        const float a = fexp2(-fmaxf(f + b - dist, 0.0f));
        const float jp = j0 * invN1, ip = i0 * invM1;
        pT += a;
        const float dt = ip - jp;
        pTe += a * dt * dt;
        int s = -1;
        for (int q = 0; q < nseg && q < MAXSEG; ++q)
            if (i0 >= sgb[q] && i0 < sgb[q + 1]) s = q;
        if (s >= 0) { atomicAdd(&sseg[s], a); atomicAdd(&ssegp[s], a * jp); }
        for (int q = 0; q < ngb && q <= MAXSEG; ++q) {
            const int bv = sgb[q];
            if (bv > 0 && bv < MM && i0 == bv) {
                const float dv = jp - (float)bv * invM1;
                pB += a * dv * dv;
            }
        }
    }
    pT = wave_red(pT); pTe = wave_red(pTe); pB = wave_red(pB);
    if ((tid & 63) == 0) {
        if (pT  != 0.f) atomicAdd(&acc[0], pT);
        if (pTe != 0.f) atomicAdd(&acc[1], pTe);
        if (pB  != 0.f) atomicAdd(&acc[2], pB);
    }
    __syncthreads();
    if (tid < nseg && tid < MAXSEG) {
        if (sseg[tid]  != 0.f) atomicAdd(&acc[3 + tid], sseg[tid]);
        if (ssegp[tid] != 0.f) atomicAdd(&acc[3 + MAXSEG + tid], ssegp[tid]);
    }
}

// ---------------------------------------------------------------------------
// Scalar epilogue replicating the reference's scale/order/coverage semantics.
// ---------------------------------------------------------------------------
__global__ void final_kernel(const float* __restrict__ acc,
                             const float* __restrict__ fwdD,
                             const int* __restrict__ gbp, int ngb,
                             float* __restrict__ out) {
    if (threadIdx.x != 0 || blockIdx.x != 0) return;
    const float dist = fwdD[TOTCELLS - 1] * UNSCALE;   // unscale shape loss
    const float Utot = acc[0];
    const float scale = (Utot > 1e-8f) ? ((float)(MM < NN ? MM : NN) / fmaxf(Utot, 1e-8f)) : 1.0f;
    const float temporal = scale * acc[1];

    int gb[MAXSEG + 1];
    const int n = (ngb <= MAXSEG + 1) ? ngb : (MAXSEG + 1);
    for (int q = 0; q < n; ++q) gb[q] = gbp[q];

    int nint = 0;
    for (int q = 0; q < n; ++q) if (gb[q] > 0 && gb[q] < MM) nint++;
    const float boundary = (nint > 0) ? (scale * acc[2] / (float)nint) : 0.f;

    float order = 0.f;
    if (n > 2) {
        float pos[MAXSEG];
        int np = 0;
        for (int s = 0; s + 1 < n; ++s) {
            const int st = gb[s], en = gb[s + 1];
            if (st >= MM || en > MM || st >= en) continue;
            const float mass = fmaxf(scale * acc[3 + s], 1e-8f);
            pos[np++] = scale * acc[3 + MAXSEG + s] / mass;
        }
        for (int k = 1; k < np; ++k) order += fmaxf(pos[k - 1] - pos[k], 0.f);
        if (np > 1) order /= (float)(np - 1);
    }

    float cov = 0.f;
    const int nsteps = n - 1;
    if (nsteps > 0) {
        for (int s = 0; s < nsteps; ++s) {
            const int st = gb[s];
            int en = gb[s + 1]; if (en > MM) en = MM;
            if (st >= en) continue;
            cov += fmaxf((float)(en - st) * 0.5f - scale * acc[3 + s], 0.f);
        }
        cov /= (float)nsteps;
    }

    out[0] = 0.3f * dist + 0.2f * temporal + 0.2f * boundary + 0.15f * order + 0.15f * cov;
}

// ---------------------------------------------------------------------------
extern "C" void kernel_launch(void* const* d_in, const int* in_sizes, int n_in,
                              void* d_out, int out_size, void* d_ws, size_t ws_size,
                              hipStream_t stream) {
    const float* pred   = (const float*)d_in[0];   // (2048, 64)
    const float* target = (const float*)d_in[1];   // (2048, 64)
    const int*   gb     = (const int*)d_in[2];     // (9,)
    const int ngb = in_sizes[2];

    float* costD = (float*)d_ws;
    float* fwdD  = costD + TOTCELLS;
    float* bwdD  = fwdD + TOTCELLS;
    float* acc   = bwdD + TOTCELLS;                 // 64 floats
    unsigned* flagsP = (unsigned*)(acc + 64);       // [2][4] producer progress
    unsigned* cprogP = flagsP + 2 * NWGD;           // [2][4] consumer progress
    float* gringP    = (float*)(cprogP + 2 * NWGD); // [2][3][GRING]

    cost_kernel<<<dim3(NN / 64, MM / 64), 256, 0, stream>>>(pred, target, costD, acc);
    dp_pipe<<<2 * NWGD, NWAVE * 64, 0, stream>>>(costD, fwdD, bwdD, flagsP, cprogP, gringP);
    combine_kernel<<<NDIAG, 256, 0, stream>>>(fwdD, bwdD, gb, ngb, acc);
    final_kernel<<<1, 64, 0, stream>>>(acc, fwdD, gb, ngb, (float*)d_out);
}

// Round 3
// 2691.537 us; speedup vs baseline: 1.7621x; 1.3990x over previous
//
#include <hip/hip_runtime.h>

#define MM 2048
#define NN 2048
#define DD 64
#define NDIAG (MM + NN - 1)      /* 4095 cost-matrix anti-diagonals */
#define TOTCELLS (MM * NN)
#define MAXSEG 15

// ---- skewed-pipeline DP geometry ----
#define NWGD   4                 /* workgroups per direction               */
#define NWAVE  4                 /* waves per WG (1 strip per wave)        */
#define STRIPROWS 128            /* rows per strip (2 per lane)            */
#define KSTEP  32                /* steps per superstep (barrier cadence)  */
#define PFD    16                /* cost prefetch depth (steps)            */
#define TSTEPS 5120              /* >= 4094 + Og(15)=1008 + 1; 160*32      */
#define NSUPER (TSTEPS / KSTEP)
#define GRING  1024              /* global ring entries per WG boundary    */
#define LRING  256               /* LDS ring entries per strip boundary    */
// Strip g skew: Og = 48g + 96*(g/4)  (intra-WG lag 49, inter-WG lag 145;
// both ≡0 mod 16 so prefetch slots are compile-time static).
// S_use(g) = Og + 128g = 176g + 96*(g/4); consumer columns ec = t - S_use.

constexpr float K2      = 14.426950408889634f;   // log2(e)/gamma, gamma=0.1
constexpr float INF_K   = 1.0e10f * 14.426950408889634f;
constexpr float UNSCALE = 0.06931471805599453f;  // gamma*ln2 = 1/K2

// Packed anti-diagonal layout for a 2048x2048 matrix: diag d = i+j, 0..4094.
__device__ __forceinline__ int diag_off(int d) {
    return (d < NN) ? ((d * (d + 1)) >> 1)
                    : (TOTCELLS - (((NDIAG - d) * (NDIAG - d + 1)) >> 1));
}
__device__ __forceinline__ int diag_imin(int d) { return (d < NN) ? 0 : (d - (NN - 1)); }
__device__ __forceinline__ int diag_len(int d)  { return (d < NN) ? (d + 1) : (NDIAG - d); }

__device__ __forceinline__ float fexp2(float x) { return __builtin_amdgcn_exp2f(x); }
__device__ __forceinline__ float flog2(float x) { return __builtin_amdgcn_logf(x); }

// softmin in the K2-scaled (log2) domain, stable: m1 - log2(1 + 2^(m1-m2) + 2^(m1-m3))
__device__ __forceinline__ float softmin3k(float a, float b, float c) {
    const float m1 = fminf(fminf(a, b), c);
    const float m2 = __builtin_amdgcn_fmed3f(a, b, c);
    const float m3 = fmaxf(fmaxf(a, b), c);
    const float e  = 1.0f + fexp2(m1 - m2) + fexp2(m1 - m3);
    return m1 - flog2(e);
}

// ---------------------------------------------------------------------------
// cost[i,j] = K2 * sum_k (target[i,k]-pred[j,k])^2, packed diag layout.
// Block (0,0) also zeroes accumulators + pipeline flags (80 words).
// ---------------------------------------------------------------------------
__global__ __launch_bounds__(256) void cost_kernel(const float* __restrict__ pred,
                                                   const float* __restrict__ target,
                                                   float* __restrict__ costD,
                                                   float* __restrict__ acc) {
    __shared__ float Ts[64][65];
    __shared__ float Ps[64][65];
    const int tid = threadIdx.x;
    const int tx = tid & 15, ty = tid >> 4;
    const int i0 = blockIdx.y * 64;
    const int j0 = blockIdx.x * 64;

    if (blockIdx.x == 0 && blockIdx.y == 0 && tid < 80) ((unsigned*)acc)[tid] = 0u;

    #pragma unroll
    for (int rnd = 0; rnd < 4; ++rnd) {
        int f4i = tid + rnd * 256;
        int r  = f4i >> 4;
        int k4 = (f4i & 15) << 2;
        float4 tv = *reinterpret_cast<const float4*>(target + (size_t)(i0 + r) * DD + k4);
        Ts[r][k4 + 0] = tv.x; Ts[r][k4 + 1] = tv.y; Ts[r][k4 + 2] = tv.z; Ts[r][k4 + 3] = tv.w;
        float4 pv = *reinterpret_cast<const float4*>(pred + (size_t)(j0 + r) * DD + k4);
        Ps[k4 + 0][r] = pv.x; Ps[k4 + 1][r] = pv.y; Ps[k4 + 2][r] = pv.z; Ps[k4 + 3][r] = pv.w;
    }
    __syncthreads();

    float accv[4][4];
    #pragma unroll
    for (int a = 0; a < 4; ++a)
        #pragma unroll
        for (int b = 0; b < 4; ++b) accv[a][b] = 0.f;

    for (int k = 0; k < 64; ++k) {
        float ta[4], pb[4];
        #pragma unroll
        for (int a = 0; a < 4; ++a) ta[a] = Ts[ty + 16 * a][k];
        #pragma unroll
        for (int b = 0; b < 4; ++b) pb[b] = Ps[k][tx + 16 * b];
        #pragma unroll
        for (int a = 0; a < 4; ++a)
            #pragma unroll
            for (int b = 0; b < 4; ++b) {
                float d = ta[a] - pb[b];
                accv[a][b] = fmaf(d, d, accv[a][b]);
            }
    }
    #pragma unroll
    for (int a = 0; a < 4; ++a) {
        int i = i0 + ty + 16 * a;
        #pragma unroll
        for (int b = 0; b < 4; ++b) {
            int j = j0 + tx + 16 * b;
            int d = i + j;
            costD[diag_off(d) + (i - diag_imin(d))] = accv[a][b] * K2;
        }
    }
}

// ---------------------------------------------------------------------------
// Skewed register-resident soft-DTW. blocks 0-3: forward -> fwdD (scaled R).
// blocks 4-7: backward as forward on the 180-rotated cost -> bwdD, using the
// packed-layout identity flat_orig = TOTCELLS-1-flat_rot (so combine reads
// bwdD with original-layout indexing and gets B = b + c at each cell).
// Lane l of strip g owns rows 128g+2l(+1); at wall-step t it computes both
// cells of diagonal dd = t - Og. Cost is register-prefetched 16 steps deep;
// the boundary-row LDS ring is prefetched 2 steps deep; WG boundaries have
// 2 supersteps of slack so the producer flag is always already set.
// ---------------------------------------------------------------------------
__global__ __launch_bounds__(256) void dp_pipe(const float* __restrict__ costD,
                                               float* __restrict__ fwdD,
                                               float* __restrict__ bwdD,
                                               unsigned* __restrict__ flagsP,
                                               float* __restrict__ gringP) {
    __shared__ float ring[NWAVE + 1][LRING];   // rows 0-3: strip publishes; row 4: gather
    const int dir  = (int)blockIdx.x >> 2;
    const int wg   = (int)blockIdx.x & 3;
    const int tid  = threadIdx.x;
    const int wv   = tid >> 6;
    const int lane = tid & 63;
    const int g    = wg * NWAVE + wv;
    const int Og   = __builtin_amdgcn_readfirstlane(48 * g + 96 * (g >> 2));
    const int Suse = __builtin_amdgcn_readfirstlane(176 * g + 96 * (g >> 2));
    const int r0   = STRIPROWS * g + 2 * lane;
    float* __restrict__ outD = dir ? bwdD : fwdD;
    unsigned* pf = flagsP + dir * NWGD;
    float* grd   = gringP + (size_t)dir * 3 * GRING;
    const float* mring = ring[(wv == 0) ? NWAVE : (wv - 1)];
    const int shl = (lane + 63) & 63;
    const int sgn = dir ? -1 : 1;

    // incremental per-lane addresses: aS tracks diag dd, aL tracks diag dd+PFD
    int aS, aL;
    {
        const int b0  = r0;                       // flat_rot at dd=0
        const int b16 = 136 + r0;                 // off(16)=136, im=0
        const int s0  = (g == 0) ? b16 : b0;
        aS = dir ? (TOTCELLS - 1 - b0) : b0;
        aL = dir ? (TOTCELLS - 1 - s0) : s0;
    }

    float cc0[PFD], cc1[PFD];
    float Rk0 = INF_K, Rk0m1 = INF_K, Rk1 = INF_K;
    float dg0 = (g == 0 && lane == 0) ? 0.0f : INF_K;  // virtual R[0,0]=0
    float ext[4] = {INF_K, INF_K, INF_K, INF_K};

    // prologue: strip 0 fills slots for dd = 0..15
    if (g == 0) {
        #pragma unroll
        for (int p = 0; p < PFD; ++p) {
            const int off = (p * (p + 1)) >> 1;
            const int b = dir ? (TOTCELLS - 1 - off - r0) : (off + r0);
            cc0[p] = costD[b];
            cc1[p] = costD[b + sgn];
        }
    }

    for (unsigned m = 0; m < NSUPER; ++m) {
        const int tbase = (int)(m * KSTEP);

        // ---- inter-WG gather (wv0, wg>0): columns [c0g, c0g+63] -> ring[4]
        if (wv == 0 && wg > 0) {
            const int c0g = tbase - Suse;
            if (c0g + 63 >= 0 && c0g < NN) {
                const unsigned need = m - 1;       // producer is ~1 superstep past this
                unsigned guard = 0;
                while (__hip_atomic_load(&pf[wg - 1], __ATOMIC_ACQUIRE,
                                         __HIP_MEMORY_SCOPE_AGENT) < need &&
                       guard < (1u << 20)) { __builtin_amdgcn_s_sleep(8); ++guard; }
                const int c = c0g + lane;
                if (c >= 0 && c < NN)
                    ring[NWAVE][c & (LRING - 1)] =
                        __hip_atomic_load(&grd[(wg - 1) * GRING + (c & (GRING - 1))],
                                          __ATOMIC_RELAXED, __HIP_MEMORY_SCOPE_AGENT);
            }
        }

        // ---- 32 wavefront steps (two 16-unrolled groups; slots static)
        for (int tu = 0; tu < KSTEP; tu += PFD) {
            #pragma unroll
            for (int q = 0; q < PFD; ++q) {
                const int t  = tbase + tu + q;
                const int dd = t - Og;             // wave-uniform (SALU guard)
                const int ddL = dd + PFD;
                if (ddL >= 0 && ddL < NDIAG) {     // refill slot q for diag ddL
                    cc0[q] = costD[aL];
                    cc1[q] = costD[aL + sgn];
                    const int dl = (ddL + 1 < NDIAG - 1 - ddL) ? (ddL + 1) : (NDIAG - 1 - ddL);
                    aL += sgn * dl;
                }
                if (dd >= 0 && dd < NDIAG) {
                    const int ec = t - Suse;       // boundary column this step
                    float extv = INF_K;
                    if (g != 0 && ec >= 0 && ec < NN) extv = ext[q & 3];
                    if (g != 0)                    // prefetch ring value for step t+2
                        ext[(q + 2) & 3] = mring[((unsigned)(t + 2 - Suse)) & (LRING - 1)];
                    const float shr = __shfl(Rk1, shl, 64);
                    const float up0 = (lane == 0) ? extv : shr;
                    const float n0 = cc0[q] + softmin3k(dg0, up0, Rk0);
                    const float n1 = cc1[q] + softmin3k(Rk0m1, Rk0, Rk1);
                    const int c0 = dd - r0;
                    const bool v0 = (c0 >= 0) && (c0 < NN);
                    const bool v1 = (c0 >= 1) && (c0 <= NN);
                    Rk0m1 = Rk0;
                    if (v0) Rk0 = n0;
                    if (v1) Rk1 = n1;
                    dg0 = up0;
                    if (v0) outD[aS] = Rk0;
                    if (v1) outD[aS + sgn] = Rk1;
                    const int pc = ec - (STRIPROWS - 1);   // publish last row (lane 63)
                    if (lane == 63 && pc >= 0 && pc < NN)
                        ring[wv][pc & (LRING - 1)] = Rk1;
                    const int ds = (dd + 1 < NDIAG - 1 - dd) ? (dd + 1) : (NDIAG - 1 - dd);
                    aS += sgn * ds;
                }
            }
        }
        __syncthreads();

        // ---- inter-WG flush (wv0): ring[3] -> global ring, then flag
        if (wv == 0 && wg < NWGD - 1) {
            const int Sp = 800 * wg + 528;          // S_use of strip 4wg+3
            const int cb = tbase - Sp - (STRIPROWS - 1);
            if (lane < KSTEP) {
                const int c = cb + lane;
                if (c >= 0 && c < NN)
                    __hip_atomic_store(&grd[wg * GRING + (c & (GRING - 1))],
                                       ring[NWAVE - 1][c & (LRING - 1)],
                                       __ATOMIC_RELAXED, __HIP_MEMORY_SCOPE_AGENT);
            }
            if (lane == 0)
                __hip_atomic_store(&pf[wg], m + 1, __ATOMIC_RELEASE,
                                   __HIP_MEMORY_SCOPE_AGENT);
        }
    }
}

// ---------------------------------------------------------------------------
// Per-cell alignment + linear reductions. a = exp2(-max(f + B - dist, 0)).
// acc: [0]=total [1]=temporal [2]=boundary [3..17]=seg mass [18..32]=seg pos
// ---------------------------------------------------------------------------
__device__ __forceinline__ float wave_red(float v) {
    v += __shfl_xor(v, 32, 64);
    v += __shfl_xor(v, 16, 64);
    v += __shfl_xor(v, 8, 64);
    v += __shfl_xor(v, 4, 64);
    v += __shfl_xor(v, 2, 64);
    v += __shfl_xor(v, 1, 64);
    return v;
}

__global__ __launch_bounds__(256) void combine_kernel(const float* __restrict__ fwdD,
                                                      const float* __restrict__ bwdD,
                                                      const int* __restrict__ gbp, int ngb,
                                                      float* __restrict__ acc) {
    const int d = blockIdx.x;
    const int ofs = diag_off(d), imin = diag_imin(d), len = diag_len(d);
    const float dist = fwdD[TOTCELLS - 1];
    __shared__ float sseg[MAXSEG], ssegp[MAXSEG];
    __shared__ int sgb[MAXSEG + 1];
    const int tid = threadIdx.x;
    if (tid < MAXSEG) { sseg[tid] = 0.f; ssegp[tid] = 0.f; }
    if (tid < ngb && tid <= MAXSEG) sgb[tid] = gbp[tid];
    __syncthreads();

    float pT = 0.f, pTe = 0.f, pB = 0.f;
    const float invM1 = 1.f / (float)(MM - 1);
    const float invN1 = 1.f / (float)(NN - 1);
    const int nseg = ngb - 1;

    for (int x = tid; x < len; x += 256) {
        const int i0 = imin + x, j0 = d - i0;
        const float f = fwdD[ofs + x], b = bwdD[ofs + x];
        const float a = fexp2(-fmaxf(f + b - dist, 0.0f));
        const float jp = j0 * invN1, ip = i0 * invM1;
        pT += a;
        const float dt = ip - jp;
        pTe += a * dt * dt;
        int s = -1;
        for (int q = 0; q < nseg && q < MAXSEG; ++q)
            if (i0 >= sgb[q] && i0 < sgb[q + 1]) s = q;
        if (s >= 0) { atomicAdd(&sseg[s], a); atomicAdd(&ssegp[s], a * jp); }
        for (int q = 0; q < ngb && q <= MAXSEG; ++q) {
            const int bv = sgb[q];
            if (bv > 0 && bv < MM && i0 == bv) {
                const float dv = jp - (float)bv * invM1;
                pB += a * dv * dv;
            }
        }
    }
    pT = wave_red(pT); pTe = wave_red(pTe); pB = wave_red(pB);
    if ((tid & 63) == 0) {
        if (pT  != 0.f) atomicAdd(&acc[0], pT);
        if (pTe != 0.f) atomicAdd(&acc[1], pTe);
        if (pB  != 0.f) atomicAdd(&acc[2], pB);
    }
    __syncthreads();
    if (tid < nseg && tid < MAXSEG) {
        if (sseg[tid]  != 0.f) atomicAdd(&acc[3 + tid], sseg[tid]);
        if (ssegp[tid] != 0.f) atomicAdd(&acc[3 + MAXSEG + tid], ssegp[tid]);
    }
}

// ---------------------------------------------------------------------------
// Scalar epilogue replicating the reference's scale/order/coverage semantics.
// ---------------------------------------------------------------------------
__global__ void final_kernel(const float* __restrict__ acc,
                             const float* __restrict__ fwdD,
                             const int* __restrict__ gbp, int ngb,
                             float* __restrict__ out) {
    if (threadIdx.x != 0 || blockIdx.x != 0) return;
    const float dist = fwdD[TOTCELLS - 1] * UNSCALE;   // unscale shape loss
    const float Utot = acc[0];
    const float scale = (Utot > 1e-8f) ? ((float)(MM < NN ? MM : NN) / fmaxf(Utot, 1e-8f)) : 1.0f;
    const float temporal = scale * acc[1];

    int gb[MAXSEG + 1];
    const int n = (ngb <= MAXSEG + 1) ? ngb : (MAXSEG + 1);
    for (int q = 0; q < n; ++q) gb[q] = gbp[q];

    int nint = 0;
    for (int q = 0; q < n; ++q) if (gb[q] > 0 && gb[q] < MM) nint++;
    const float boundary = (nint > 0) ? (scale * acc[2] / (float)nint) : 0.f;

    float order = 0.f;
    if (n > 2) {
        float pos[MAXSEG];
        int np = 0;
        for (int s = 0; s + 1 < n; ++s) {
            const int st = gb[s], en = gb[s + 1];
            if (st >= MM || en > MM || st >= en) continue;
            const float mass = fmaxf(scale * acc[3 + s], 1e-8f);
            pos[np++] = scale * acc[3 + MAXSEG + s] / mass;
        }
        for (int k = 1; k < np; ++k) order += fmaxf(pos[k - 1] - pos[k], 0.f);
        if (np > 1) order /= (float)(np - 1);
    }

    float cov = 0.f;
    const int nsteps = n - 1;
    if (nsteps > 0) {
        for (int s = 0; s < nsteps; ++s) {
            const int st = gb[s];
            int en = gb[s + 1]; if (en > MM) en = MM;
            if (st >= en) continue;
            cov += fmaxf((float)(en - st) * 0.5f - scale * acc[3 + s], 0.f);
        }
        cov /= (float)nsteps;
    }

    out[0] = 0.3f * dist + 0.2f * temporal + 0.2f * boundary + 0.15f * order + 0.15f * cov;
}

// ---------------------------------------------------------------------------
extern "C" void kernel_launch(void* const* d_in, const int* in_sizes, int n_in,
                              void* d_out, int out_size, void* d_ws, size_t ws_size,
                              hipStream_t stream) {
    const float* pred   = (const float*)d_in[0];   // (2048, 64)
    const float* target = (const float*)d_in[1];   // (2048, 64)
    const int*   gb     = (const int*)d_in[2];     // (9,)
    const int ngb = in_sizes[2];

    float* costD = (float*)d_ws;
    float* fwdD  = costD + TOTCELLS;
    float* bwdD  = fwdD + TOTCELLS;
    float* acc   = bwdD + TOTCELLS;                 // 64 floats (zeroed by cost_kernel)
    unsigned* flagsP = (unsigned*)(acc + 64);       // [2][4] producer progress (zeroed)
    float* gringP    = (float*)(flagsP + 2 * NWGD); // [2][3][GRING]

    cost_kernel<<<dim3(NN / 64, MM / 64), 256, 0, stream>>>(pred, target, costD, acc);
    dp_pipe<<<2 * NWGD, NWAVE * 64, 0, stream>>>(costD, fwdD, bwdD, flagsP, gringP);
    combine_kernel<<<NDIAG, 256, 0, stream>>>(fwdD, bwdD, gb, ngb, acc);
    final_kernel<<<1, 64, 0, stream>>>(acc, fwdD, gb, ngb, (float*)d_out);
}

// Round 4
// 2639.878 us; speedup vs baseline: 1.7966x; 1.0196x over previous
//
#include <hip/hip_runtime.h>

#define MM 2048
#define NN 2048
#define DD 64
#define NDIAG (MM + NN - 1)      /* 4095 cost-matrix anti-diagonals */
#define TOTCELLS (MM * NN)
#define MAXSEG 15

// ---- skewed-pipeline DP geometry ----
#define NWGD   4                 /* workgroups per direction               */
#define NWAVE  4                 /* waves per WG (1 strip per wave)        */
#define STRIPROWS 128            /* rows per strip (2 per lane)            */
#define KSTEP  32                /* steps per superstep (barrier cadence)  */
#define PFD    8                 /* cost prefetch depth (steps); 4 vmem/step
                                    * 8 = 32 in-flight, under the vmcnt cap */
#define TSTEPS 5120              /* >= 4094 + Og(15)=1008 + 1; 160*32      */
#define NSUPER (TSTEPS / KSTEP)
#define GRING  1024              /* global ring entries per WG boundary    */
#define LRING  256               /* LDS ring entries per strip boundary    */
// Strip g skew: Og = 48g + 96*(g/4)  (intra-WG lag 49, inter-WG lag 145;
// both ≡0 mod PFD so prefetch slots are compile-time static).
// S_use(g) = Og + 128g = 176g + 96*(g/4); consumer columns ec = t - S_use.

constexpr float K2      = 14.426950408889634f;   // log2(e)/gamma, gamma=0.1
constexpr float INF_K   = 1.0e10f * 14.426950408889634f;
constexpr float UNSCALE = 0.06931471805599453f;  // gamma*ln2 = 1/K2

// Packed anti-diagonal layout for a 2048x2048 matrix: diag d = i+j, 0..4094.
__device__ __forceinline__ int diag_off(int d) {
    return (d < NN) ? ((d * (d + 1)) >> 1)
                    : (TOTCELLS - (((NDIAG - d) * (NDIAG - d + 1)) >> 1));
}
__device__ __forceinline__ int diag_imin(int d) { return (d < NN) ? 0 : (d - (NN - 1)); }
__device__ __forceinline__ int diag_len(int d)  { return (d < NN) ? (d + 1) : (NDIAG - d); }

__device__ __forceinline__ float fexp2(float x) { return __builtin_amdgcn_exp2f(x); }
__device__ __forceinline__ float flog2(float x) { return __builtin_amdgcn_logf(x); }

// softmin in the K2-scaled (log2) domain, stable: m1 - log2(1 + 2^(m1-m2) + 2^(m1-m3))
__device__ __forceinline__ float softmin3k(float a, float b, float c) {
    const float m1 = fminf(fminf(a, b), c);
    const float m2 = __builtin_amdgcn_fmed3f(a, b, c);
    const float m3 = fmaxf(fmaxf(a, b), c);
    const float e  = 1.0f + fexp2(m1 - m2) + fexp2(m1 - m3);
    return m1 - flog2(e);
}

// ---------------------------------------------------------------------------
// cost[i,j] = K2 * sum_k (target[i,k]-pred[j,k])^2, packed diag layout.
// Block (0,0) also zeroes accumulators + pipeline flags (80 words).
// ---------------------------------------------------------------------------
__global__ __launch_bounds__(256) void cost_kernel(const float* __restrict__ pred,
                                                   const float* __restrict__ target,
                                                   float* __restrict__ costD,
                                                   float* __restrict__ acc) {
    __shared__ float Ts[64][65];
    __shared__ float Ps[64][65];
    const int tid = threadIdx.x;
    const int tx = tid & 15, ty = tid >> 4;
    const int i0 = blockIdx.y * 64;
    const int j0 = blockIdx.x * 64;

    if (blockIdx.x == 0 && blockIdx.y == 0 && tid < 80) ((unsigned*)acc)[tid] = 0u;

    #pragma unroll
    for (int rnd = 0; rnd < 4; ++rnd) {
        int f4i = tid + rnd * 256;
        int r  = f4i >> 4;
        int k4 = (f4i & 15) << 2;
        float4 tv = *reinterpret_cast<const float4*>(target + (size_t)(i0 + r) * DD + k4);
        Ts[r][k4 + 0] = tv.x; Ts[r][k4 + 1] = tv.y; Ts[r][k4 + 2] = tv.z; Ts[r][k4 + 3] = tv.w;
        float4 pv = *reinterpret_cast<const float4*>(pred + (size_t)(j0 + r) * DD + k4);
        Ps[k4 + 0][r] = pv.x; Ps[k4 + 1][r] = pv.y; Ps[k4 + 2][r] = pv.z; Ps[k4 + 3][r] = pv.w;
    }
    __syncthreads();

    float accv[4][4];
    #pragma unroll
    for (int a = 0; a < 4; ++a)
        #pragma unroll
        for (int b = 0; b < 4; ++b) accv[a][b] = 0.f;

    for (int k = 0; k < 64; ++k) {
        float ta[4], pb[4];
        #pragma unroll
        for (int a = 0; a < 4; ++a) ta[a] = Ts[ty + 16 * a][k];
        #pragma unroll
        for (int b = 0; b < 4; ++b) pb[b] = Ps[k][tx + 16 * b];
        #pragma unroll
        for (int a = 0; a < 4; ++a)
            #pragma unroll
            for (int b = 0; b < 4; ++b) {
                float d = ta[a] - pb[b];
                accv[a][b] = fmaf(d, d, accv[a][b]);
            }
    }
    #pragma unroll
    for (int a = 0; a < 4; ++a) {
        int i = i0 + ty + 16 * a;
        #pragma unroll
        for (int b = 0; b < 4; ++b) {
            int j = j0 + tx + 16 * b;
            int d = i + j;
            costD[diag_off(d) + (i - diag_imin(d))] = accv[a][b] * K2;
        }
    }
}

// ---------------------------------------------------------------------------
// Skewed register-resident soft-DTW. blocks 0-3: forward -> fwdD (scaled R).
// blocks 4-7: backward as forward on the 180-rotated cost -> bwdD, using the
// packed-layout identity flat_orig = TOTCELLS-1-flat_rot (so combine reads
// bwdD with original-layout indexing and gets B = b + c at each cell).
// Lane l of strip g owns rows 128g+2l(+1); at wall-step t it computes both
// cells of diagonal dd = t - Og. Cost is register-prefetched PFD=8 steps deep
// (CONSUME slot into locals BEFORE refilling it - the R3 clobber exposed full
// HBM latency every step); boundary LDS ring prefetched 2 steps deep; WG
// boundaries have ~2 supersteps of slack so producer flags are already set.
// ---------------------------------------------------------------------------
__global__ __launch_bounds__(256) void dp_pipe(const float* __restrict__ costD,
                                               float* __restrict__ fwdD,
                                               float* __restrict__ bwdD,
                                               unsigned* __restrict__ flagsP,
                                               float* __restrict__ gringP) {
    __shared__ float ring[NWAVE + 1][LRING];   // rows 0-3: strip publishes; row 4: gather
    const int dir  = (int)blockIdx.x >> 2;
    const int wg   = (int)blockIdx.x & 3;
    const int tid  = threadIdx.x;
    const int wv   = tid >> 6;
    const int lane = tid & 63;
    const int g    = wg * NWAVE + wv;
    const int Og   = __builtin_amdgcn_readfirstlane(48 * g + 96 * (g >> 2));
    const int Suse = __builtin_amdgcn_readfirstlane(176 * g + 96 * (g >> 2));
    const int r0   = STRIPROWS * g + 2 * lane;
    float* __restrict__ outD = dir ? bwdD : fwdD;
    unsigned* pf = flagsP + dir * NWGD;
    float* grd   = gringP + (size_t)dir * 3 * GRING;
    const float* mring = ring[(wv == 0) ? NWAVE : (wv - 1)];
    const int shl = (lane + 63) & 63;
    const int sgn = dir ? -1 : 1;

    // incremental per-lane addresses: aS tracks diag dd, aL tracks diag dd+PFD
    int aS, aL;
    {
        const int b0 = r0;                        // flat_rot at dd=0
        const int b8 = 36 + r0;                   // off(8)=36, im=0
        const int s0 = (g == 0) ? b8 : b0;
        aS = dir ? (TOTCELLS - 1 - b0) : b0;
        aL = dir ? (TOTCELLS - 1 - s0) : s0;
    }

    float cc0[PFD], cc1[PFD];
    float Rk0 = INF_K, Rk0m1 = INF_K, Rk1 = INF_K;
    float dg0 = (g == 0 && lane == 0) ? 0.0f : INF_K;  // virtual R[0,0]=0
    float ext[4] = {INF_K, INF_K, INF_K, INF_K};

    // prologue: strip 0 fills slots for dd = 0..PFD-1
    if (g == 0) {
        #pragma unroll
        for (int p = 0; p < PFD; ++p) {
            const int off = (p * (p + 1)) >> 1;
            const int b = dir ? (TOTCELLS - 1 - off - r0) : (off + r0);
            cc0[p] = costD[b];
            cc1[p] = costD[b + sgn];
        }
    }

    for (unsigned m = 0; m < NSUPER; ++m) {
        const int tbase = (int)(m * KSTEP);

        // ---- inter-WG gather (wv0, wg>0): columns [c0g, c0g+63] -> ring[4]
        if (wv == 0 && wg > 0) {
            const int c0g = tbase - Suse;
            if (c0g + 63 >= 0 && c0g < NN) {
                const unsigned need = m - 1;       // producer is ~1 superstep past this
                unsigned guard = 0;
                while (__hip_atomic_load(&pf[wg - 1], __ATOMIC_ACQUIRE,
                                         __HIP_MEMORY_SCOPE_AGENT) < need &&
                       guard < (1u << 20)) { __builtin_amdgcn_s_sleep(8); ++guard; }
                const int c = c0g + lane;
                if (c >= 0 && c < NN)
                    ring[NWAVE][c & (LRING - 1)] =
                        __hip_atomic_load(&grd[(wg - 1) * GRING + (c & (GRING - 1))],
                                          __ATOMIC_RELAXED, __HIP_MEMORY_SCOPE_AGENT);
            }
        }

        // ---- 32 wavefront steps (four 8-unrolled groups; slots static)
        for (int tu = 0; tu < KSTEP; tu += PFD) {
            #pragma unroll
            for (int q = 0; q < PFD; ++q) {
                const int t  = tbase + tu + q;
                const int dd = t - Og;             // wave-uniform (SALU guard)
                // CONSUME slot q (diag dd) into locals BEFORE refilling it
                const float uc0 = cc0[q];
                const float uc1 = cc1[q];
                const int ddL = dd + PFD;
                if (ddL >= 0 && ddL < NDIAG) {     // refill slot q for diag ddL
                    cc0[q] = costD[aL];
                    cc1[q] = costD[aL + sgn];
                    const int dl = (ddL + 1 < NDIAG - 1 - ddL) ? (ddL + 1) : (NDIAG - 1 - ddL);
                    aL += sgn * dl;
                }
                if (dd >= 0 && dd < NDIAG) {
                    const int ec = t - Suse;       // boundary column this step
                    float extv = INF_K;
                    if (g != 0 && ec >= 0 && ec < NN) extv = ext[q & 3];
                    if (g != 0)                    // prefetch ring value for step t+2
                        ext[(q + 2) & 3] = mring[((unsigned)(t + 2 - Suse)) & (LRING - 1)];
                    const float shr = __shfl(Rk1, shl, 64);
                    const float up0 = (lane == 0) ? extv : shr;
                    const float n0 = uc0 + softmin3k(dg0, up0, Rk0);
                    const float n1 = uc1 + softmin3k(Rk0m1, Rk0, Rk1);
                    const int c0 = dd - r0;
                    const bool v0 = (c0 >= 0) && (c0 < NN);
                    const bool v1 = (c0 >= 1) && (c0 <= NN);
                    Rk0m1 = Rk0;
                    if (v0) Rk0 = n0;
                    if (v1) Rk1 = n1;
                    dg0 = up0;
                    if (v0) outD[aS] = Rk0;
                    if (v1) outD[aS + sgn] = Rk1;
                    const int pc = ec - (STRIPROWS - 1);   // publish last row (lane 63)
                    if (lane == 63 && pc >= 0 && pc < NN)
                        ring[wv][pc & (LRING - 1)] = Rk1;
                    const int ds = (dd + 1 < NDIAG - 1 - dd) ? (dd + 1) : (NDIAG - 1 - dd);
                    aS += sgn * ds;
                }
            }
        }
        __syncthreads();

        // ---- inter-WG flush (wv0): ring[3] -> global ring, then flag
        if (wv == 0 && wg < NWGD - 1) {
            const int Sp = 800 * wg + 528;          // S_use of strip 4wg+3
            const int cb = tbase - Sp - (STRIPROWS - 1);
            if (lane < KSTEP) {
                const int c = cb + lane;
                if (c >= 0 && c < NN)
                    __hip_atomic_store(&grd[wg * GRING + (c & (GRING - 1))],
                                       ring[NWAVE - 1][c & (LRING - 1)],
                                       __ATOMIC_RELAXED, __HIP_MEMORY_SCOPE_AGENT);
            }
            if (lane == 0)
                __hip_atomic_store(&pf[wg], m + 1, __ATOMIC_RELEASE,
                                   __HIP_MEMORY_SCOPE_AGENT);
        }
    }
}

// ---------------------------------------------------------------------------
// Per-cell alignment + linear reductions. a = exp2(-max(f + B - dist, 0)).
// acc: [0]=total [1]=temporal [2]=boundary [3..17]=seg mass [18..32]=seg pos
// ---------------------------------------------------------------------------
__device__ __forceinline__ float wave_red(float v) {
    v += __shfl_xor(v, 32, 64);
    v += __shfl_xor(v, 16, 64);
    v += __shfl_xor(v, 8, 64);
    v += __shfl_xor(v, 4, 64);
    v += __shfl_xor(v, 2, 64);
    v += __shfl_xor(v, 1, 64);
    return v;
}

__global__ __launch_bounds__(256) void combine_kernel(const float* __restrict__ fwdD,
                                                      const float* __restrict__ bwdD,
                                                      const int* __restrict__ gbp, int ngb,
                                                      float* __restrict__ acc) {
    const int d = blockIdx.x;
    const int ofs = diag_off(d), imin = diag_imin(d), len = diag_len(d);
    const float dist = fwdD[TOTCELLS - 1];
    __shared__ float sseg[MAXSEG], ssegp[MAXSEG];
    __shared__ int sgb[MAXSEG + 1];
    const int tid = threadIdx.x;
    if (tid < MAXSEG) { sseg[tid] = 0.f; ssegp[tid] = 0.f; }
    if (tid < ngb && tid <= MAXSEG) sgb[tid] = gbp[tid];
    __syncthreads();

    float pT = 0.f, pTe = 0.f, pB = 0.f;
    const float invM1 = 1.f / (float)(MM - 1);
    const float invN1 = 1.f / (float)(NN - 1);
    const int nseg = ngb - 1;

    for (int x = tid; x < len; x += 256) {
        const int i0 = imin + x, j0 = d - i0;
        const float f = fwdD[ofs + x], b = bwdD[ofs + x];
        const float a = fexp2(-fmaxf(f + b - dist, 0.0f));
        const float jp = j0 * invN1, ip = i0 * invM1;
        pT += a;
        const float dt = ip - jp;
        pTe += a * dt * dt;
        int s = -1;
        for (int q = 0; q < nseg && q < MAXSEG; ++q)
            if (i0 >= sgb[q] && i0 < sgb[q + 1]) s = q;
        if (s >= 0) { atomicAdd(&sseg[s], a); atomicAdd(&ssegp[s], a * jp); }
        for (int q = 0; q < ngb && q <= MAXSEG; ++q) {
            const int bv = sgb[q];
            if (bv > 0 && bv < MM && i0 == bv) {
                const float dv = jp - (float)bv * invM1;
                pB += a * dv * dv;
            }
        }
    }
    pT = wave_red(pT); pTe = wave_red(pTe); pB = wave_red(pB);
    if ((tid & 63) == 0) {
        if (pT  != 0.f) atomicAdd(&acc[0], pT);
        if (pTe != 0.f) atomicAdd(&acc[1], pTe);
        if (pB  != 0.f) atomicAdd(&acc[2], pB);
    }
    __syncthreads();
    if (tid < nseg && tid < MAXSEG) {
        if (sseg[tid]  != 0.f) atomicAdd(&acc[3 + tid], sseg[tid]);
        if (ssegp[tid] != 0.f) atomicAdd(&acc[3 + MAXSEG + tid], ssegp[tid]);
    }
}

// ---------------------------------------------------------------------------
// Scalar epilogue replicating the reference's scale/order/coverage semantics.
// ---------------------------------------------------------------------------
__global__ void final_kernel(const float* __restrict__ acc,
                             const float* __restrict__ fwdD,
                             const int* __restrict__ gbp, int ngb,
                             float* __restrict__ out) {
    if (threadIdx.x != 0 || blockIdx.x != 0) return;
    const float dist = fwdD[TOTCELLS - 1] * UNSCALE;   // unscale shape loss
    const float Utot = acc[0];
    const float scale = (Utot > 1e-8f) ? ((float)(MM < NN ? MM : NN) / fmaxf(Utot, 1e-8f)) : 1.0f;
    const float temporal = scale * acc[1];

    int gb[MAXSEG + 1];
    const int n = (ngb <= MAXSEG + 1) ? ngb : (MAXSEG + 1);
    for (int q = 0; q < n; ++q) gb[q] = gbp[q];

    int nint = 0;
    for (int q = 0; q < n; ++q) if (gb[q] > 0 && gb[q] < MM) nint++;
    const float boundary = (nint > 0) ? (scale * acc[2] / (float)nint) : 0.f;

    float order = 0.f;
    if (n > 2) {
        float pos[MAXSEG];
        int np = 0;
        for (int s = 0; s + 1 < n; ++s) {
            const int st = gb[s], en = gb[s + 1];
            if (st >= MM || en > MM || st >= en) continue;
            const float mass = fmaxf(scale * acc[3 + s], 1e-8f);
            pos[np++] = scale * acc[3 + MAXSEG + s] / mass;
        }
        for (int k = 1; k < np; ++k) order += fmaxf(pos[k - 1] - pos[k], 0.f);
        if (np > 1) order /= (float)(np - 1);
    }

    float cov = 0.f;
    const int nsteps = n - 1;
    if (nsteps > 0) {
        for (int s = 0; s < nsteps; ++s) {
            const int st = gb[s];
            int en = gb[s + 1]; if (en > MM) en = MM;
            if (st >= en) continue;
            cov += fmaxf((float)(en - st) * 0.5f - scale * acc[3 + s], 0.f);
        }
        cov /= (float)nsteps;
    }

    out[0] = 0.3f * dist + 0.2f * temporal + 0.2f * boundary + 0.15f * order + 0.15f * cov;
}

// ---------------------------------------------------------------------------
extern "C" void kernel_launch(void* const* d_in, const int* in_sizes, int n_in,
                              void* d_out, int out_size, void* d_ws, size_t ws_size,
                              hipStream_t stream) {
    const float* pred   = (const float*)d_in[0];   // (2048, 64)
    const float* target = (const float*)d_in[1];   // (2048, 64)
    const int*   gb     = (const int*)d_in[2];     // (9,)
    const int ngb = in_sizes[2];

    float* costD = (float*)d_ws;
    float* fwdD  = costD + TOTCELLS;
    float* bwdD  = fwdD + TOTCELLS;
    float* acc   = bwdD + TOTCELLS;                 // 64 floats (zeroed by cost_kernel)
    unsigned* flagsP = (unsigned*)(acc + 64);       // [2][4] producer progress (zeroed)
    float* gringP    = (float*)(flagsP + 2 * NWGD); // [2][3][GRING]

    cost_kernel<<<dim3(NN / 64, MM / 64), 256, 0, stream>>>(pred, target, costD, acc);
    dp_pipe<<<2 * NWGD, NWAVE * 64, 0, stream>>>(costD, fwdD, bwdD, flagsP, gringP);
    combine_kernel<<<NDIAG, 256, 0, stream>>>(fwdD, bwdD, gb, ngb, acc);
    final_kernel<<<1, 64, 0, stream>>>(acc, fwdD, gb, ngb, (float*)d_out);
}

// Round 5
// 2617.398 us; speedup vs baseline: 1.8120x; 1.0086x over previous
//
#include <hip/hip_runtime.h>

#define MM 2048
#define NN 2048
#define DD 64
#define NDIAG (MM + NN - 1)      /* 4095 cost-matrix anti-diagonals */
#define TOTCELLS (MM * NN)
#define MAXSEG 15

// ---- skewed-pipeline DP geometry ----
#define NWGD   4                 /* workgroups per direction               */
#define NWAVE  4                 /* waves per WG (1 strip per wave)        */
#define STRIPROWS 128            /* rows per strip (2 per lane)            */
#define KSTEP  32                /* steps per superstep (barrier cadence)  */
#define PFD    8                 /* cost prefetch depth (steps)            */
#define EXTD   4                 /* LDS-ring prefetch distance (steps)     */
#define TSTEPS 4992              /* >= 4094 + Og(15)=888 + 1; 156*32       */
#define NSUPER (TSTEPS / KSTEP)
#define GRING  1024              /* global ring entries per WG boundary    */
#define LRING  256               /* LDS ring entries per strip boundary    */
// Strip g skew: Og = 40g + 96*(g/4)  (intra-WG lag 41 >= KSTEP+EXTD+1=37;
// inter-WG lag 137; both ≡0 mod PFD so prefetch slots stay static).
// S_use(g) = Og + 128g = 168g + 96*(g/4); consumer columns ec = t - S_use.

constexpr float K2      = 14.426950408889634f;   // log2(e)/gamma, gamma=0.1
constexpr float INF_K   = 1.0e10f * 14.426950408889634f;
constexpr float UNSCALE = 0.06931471805599453f;  // gamma*ln2 = 1/K2

// Packed anti-diagonal layout for a 2048x2048 matrix: diag d = i+j, 0..4094.
__device__ __forceinline__ int diag_off(int d) {
    return (d < NN) ? ((d * (d + 1)) >> 1)
                    : (TOTCELLS - (((NDIAG - d) * (NDIAG - d + 1)) >> 1));
}
__device__ __forceinline__ int diag_imin(int d) { return (d < NN) ? 0 : (d - (NN - 1)); }
__device__ __forceinline__ int diag_len(int d)  { return (d < NN) ? (d + 1) : (NDIAG - d); }

__device__ __forceinline__ float fexp2(float x) { return __builtin_amdgcn_exp2f(x); }
__device__ __forceinline__ float flog2(float x) { return __builtin_amdgcn_logf(x); }

// rotate-up-by-1 across the wave via DPP wave_ror:1 (0x13C): lane l gets
// lane (l-1)&63's value at VALU latency - replaces ds_bpermute (~120cy +
// lgkmcnt(0) on the per-step critical chain). Lane 0's result is overridden.
__device__ __forceinline__ float rot_up1(float x) {
    int xi = __builtin_bit_cast(int, x);
    int r  = __builtin_amdgcn_update_dpp(xi, xi, 0x13C, 0xF, 0xF, true);
    return __builtin_bit_cast(float, r);
}

// softmin in the K2-scaled (log2) domain, stable: m1 - log2(1 + 2^(m1-m2) + 2^(m1-m3))
__device__ __forceinline__ float softmin3k(float a, float b, float c) {
    const float m1 = fminf(fminf(a, b), c);
    const float m2 = __builtin_amdgcn_fmed3f(a, b, c);
    const float m3 = fmaxf(fmaxf(a, b), c);
    const float e  = 1.0f + fexp2(m1 - m2) + fexp2(m1 - m3);
    return m1 - flog2(e);
}

// ---------------------------------------------------------------------------
// cost[i,j] = K2 * sum_k (target[i,k]-pred[j,k])^2, packed diag layout.
// Block (0,0) also zeroes accumulators + pipeline flags (80 words).
// ---------------------------------------------------------------------------
__global__ __launch_bounds__(256) void cost_kernel(const float* __restrict__ pred,
                                                   const float* __restrict__ target,
                                                   float* __restrict__ costD,
                                                   float* __restrict__ acc) {
    __shared__ float Ts[64][65];
    __shared__ float Ps[64][65];
    const int tid = threadIdx.x;
    const int tx = tid & 15, ty = tid >> 4;
    const int i0 = blockIdx.y * 64;
    const int j0 = blockIdx.x * 64;

    if (blockIdx.x == 0 && blockIdx.y == 0 && tid < 80) ((unsigned*)acc)[tid] = 0u;

    #pragma unroll
    for (int rnd = 0; rnd < 4; ++rnd) {
        int f4i = tid + rnd * 256;
        int r  = f4i >> 4;
        int k4 = (f4i & 15) << 2;
        float4 tv = *reinterpret_cast<const float4*>(target + (size_t)(i0 + r) * DD + k4);
        Ts[r][k4 + 0] = tv.x; Ts[r][k4 + 1] = tv.y; Ts[r][k4 + 2] = tv.z; Ts[r][k4 + 3] = tv.w;
        float4 pv = *reinterpret_cast<const float4*>(pred + (size_t)(j0 + r) * DD + k4);
        Ps[k4 + 0][r] = pv.x; Ps[k4 + 1][r] = pv.y; Ps[k4 + 2][r] = pv.z; Ps[k4 + 3][r] = pv.w;
    }
    __syncthreads();

    float accv[4][4];
    #pragma unroll
    for (int a = 0; a < 4; ++a)
        #pragma unroll
        for (int b = 0; b < 4; ++b) accv[a][b] = 0.f;

    for (int k = 0; k < 64; ++k) {
        float ta[4], pb[4];
        #pragma unroll
        for (int a = 0; a < 4; ++a) ta[a] = Ts[ty + 16 * a][k];
        #pragma unroll
        for (int b = 0; b < 4; ++b) pb[b] = Ps[k][tx + 16 * b];
        #pragma unroll
        for (int a = 0; a < 4; ++a)
            #pragma unroll
            for (int b = 0; b < 4; ++b) {
                float d = ta[a] - pb[b];
                accv[a][b] = fmaf(d, d, accv[a][b]);
            }
    }
    #pragma unroll
    for (int a = 0; a < 4; ++a) {
        int i = i0 + ty + 16 * a;
        #pragma unroll
        for (int b = 0; b < 4; ++b) {
            int j = j0 + tx + 16 * b;
            int d = i + j;
            costD[diag_off(d) + (i - diag_imin(d))] = accv[a][b] * K2;
        }
    }
}

// ---------------------------------------------------------------------------
// Skewed register-resident soft-DTW. blocks 0-3: forward -> fwdD (scaled R).
// blocks 4-7: backward as forward on the 180-rotated cost -> bwdD (identity
// flat_orig = TOTCELLS-1-flat_rot, so combine reads bwdD with original
// indexing and gets B = b + c at each cell). Lane l of strip g owns rows
// 128g+2l(+1); at wall-step t it computes both cells of diagonal dd = t-Og.
// Per-step chain is register-only: cost prefetched PFD=8 steps deep (consume
// slot before refilling it), cross-lane handoff via DPP wave_ror:1 (VALU),
// boundary LDS ring prefetched EXTD=4 steps deep. WG boundaries have ~2
// supersteps of slack so producer flags are already set when polled.
// ---------------------------------------------------------------------------
__global__ __launch_bounds__(256) void dp_pipe(const float* __restrict__ costD,
                                               float* __restrict__ fwdD,
                                               float* __restrict__ bwdD,
                                               unsigned* __restrict__ flagsP,
                                               float* __restrict__ gringP) {
    __shared__ float ring[NWAVE + 1][LRING];   // rows 0-3: strip publishes; row 4: gather
    const int dir  = (int)blockIdx.x >> 2;
    const int wg   = (int)blockIdx.x & 3;
    const int tid  = threadIdx.x;
    const int wv   = tid >> 6;
    const int lane = tid & 63;
    const int g    = wg * NWAVE + wv;
    const int Og   = __builtin_amdgcn_readfirstlane(40 * g + 96 * (g >> 2));
    const int Suse = __builtin_amdgcn_readfirstlane(168 * g + 96 * (g >> 2));
    const int r0   = STRIPROWS * g + 2 * lane;
    float* __restrict__ outD = dir ? bwdD : fwdD;
    unsigned* pf = flagsP + dir * NWGD;
    float* grd   = gringP + (size_t)dir * 3 * GRING;
    const float* mring = ring[(wv == 0) ? NWAVE : (wv - 1)];
    const int sgn = dir ? -1 : 1;

    // incremental per-lane addresses: aS tracks diag dd, aL tracks diag dd+PFD
    int aS, aL;
    {
        const int b0 = r0;                        // flat_rot at dd=0
        const int b8 = 36 + r0;                   // off(8)=36, im=0
        const int s0 = (g == 0) ? b8 : b0;
        aS = dir ? (TOTCELLS - 1 - b0) : b0;
        aL = dir ? (TOTCELLS - 1 - s0) : s0;
    }

    float cc0[PFD], cc1[PFD];
    float Rk0 = INF_K, Rk0m1 = INF_K, Rk1 = INF_K;
    float dg0 = (g == 0 && lane == 0) ? 0.0f : INF_K;  // virtual R[0,0]=0
    float ext[8];
    #pragma unroll
    for (int z = 0; z < 8; ++z) ext[z] = INF_K;

    // prologue: strip 0 fills slots for dd = 0..PFD-1
    if (g == 0) {
        #pragma unroll
        for (int p = 0; p < PFD; ++p) {
            const int off = (p * (p + 1)) >> 1;
            const int b = dir ? (TOTCELLS - 1 - off - r0) : (off + r0);
            cc0[p] = costD[b];
            cc1[p] = costD[b + sgn];
        }
    }

    for (unsigned m = 0; m < NSUPER; ++m) {
        const int tbase = (int)(m * KSTEP);

        // ---- inter-WG gather (wv0, wg>0): columns [c0g, c0g+63] -> ring[4]
        if (wv == 0 && wg > 0) {
            const int c0g = tbase - Suse;
            if (c0g + 63 >= 0 && c0g < NN) {
                const unsigned need = m - 1;       // producer is ~1 superstep past this
                unsigned guard = 0;
                while (__hip_atomic_load(&pf[wg - 1], __ATOMIC_ACQUIRE,
                                         __HIP_MEMORY_SCOPE_AGENT) < need &&
                       guard < (1u << 20)) { __builtin_amdgcn_s_sleep(8); ++guard; }
                const int c = c0g + lane;
                if (c >= 0 && c < NN)
                    ring[NWAVE][c & (LRING - 1)] =
                        __hip_atomic_load(&grd[(wg - 1) * GRING + (c & (GRING - 1))],
                                          __ATOMIC_RELAXED, __HIP_MEMORY_SCOPE_AGENT);
            }
        }

        // ---- 32 wavefront steps (four 8-unrolled groups; slots static)
        for (int tu = 0; tu < KSTEP; tu += PFD) {
            #pragma unroll
            for (int q = 0; q < PFD; ++q) {
                const int t  = tbase + tu + q;
                const int dd = t - Og;             // wave-uniform (SALU guard)
                // CONSUME slot q (diag dd) into locals BEFORE refilling it
                const float uc0 = cc0[q];
                const float uc1 = cc1[q];
                const int ddL = dd + PFD;
                if (ddL >= 0 && ddL < NDIAG) {     // refill slot q for diag ddL
                    cc0[q] = costD[aL];
                    cc1[q] = costD[aL + sgn];
                    const int dl = (ddL + 1 < NDIAG - 1 - ddL) ? (ddL + 1) : (NDIAG - 1 - ddL);
                    aL += sgn * dl;
                }
                if (dd >= 0 && dd < NDIAG) {
                    const int ec = t - Suse;       // boundary column this step
                    // consume ext slot (written EXTD steps ago), then refill
                    float extv = INF_K;
                    if (g != 0 && ec >= 0 && ec < NN) extv = ext[q];
                    if (g != 0)                    // prefetch ring value for step t+EXTD
                        ext[(q + EXTD) & 7] =
                            mring[((unsigned)(t + EXTD - Suse)) & (LRING - 1)];
                    const float shr = rot_up1(Rk1);          // neighbor row r0-1 (VALU)
                    const float up0 = (lane == 0) ? extv : shr;
                    const float n0 = uc0 + softmin3k(dg0, up0, Rk0);
                    const float n1 = uc1 + softmin3k(Rk0m1, Rk0, Rk1);
                    const int c0 = dd - r0;
                    const bool v0 = (c0 >= 0) && (c0 < NN);
                    const bool v1 = (c0 >= 1) && (c0 <= NN);
                    Rk0m1 = Rk0;
                    if (v0) Rk0 = n0;
                    if (v1) Rk1 = n1;
                    dg0 = up0;
                    if (v0) outD[aS] = Rk0;
                    if (v1) outD[aS + sgn] = Rk1;
                    const int pc = ec - (STRIPROWS - 1);   // publish last row (lane 63)
                    if (lane == 63 && pc >= 0 && pc < NN)
                        ring[wv][pc & (LRING - 1)] = Rk1;
                    const int ds = (dd + 1 < NDIAG - 1 - dd) ? (dd + 1) : (NDIAG - 1 - dd);
                    aS += sgn * ds;
                }
            }
        }
        __syncthreads();

        // ---- inter-WG flush (wv0): ring[3] -> global ring, then flag
        if (wv == 0 && wg < NWGD - 1) {
            const int Sp = 768 * wg + 504;          // S_use of strip 4wg+3
            const int cb = tbase - Sp - (STRIPROWS - 1);
            if (lane < KSTEP) {
                const int c = cb + lane;
                if (c >= 0 && c < NN)
                    __hip_atomic_store(&grd[wg * GRING + (c & (GRING - 1))],
                                       ring[NWAVE - 1][c & (LRING - 1)],
                                       __ATOMIC_RELAXED, __HIP_MEMORY_SCOPE_AGENT);
            }
            if (lane == 0)
                __hip_atomic_store(&pf[wg], m + 1, __ATOMIC_RELEASE,
                                   __HIP_MEMORY_SCOPE_AGENT);
        }
    }
}

// ---------------------------------------------------------------------------
// Per-cell alignment + linear reductions. a = exp2(-max(f + B - dist, 0)).
// acc: [0]=total [1]=temporal [2]=boundary [3..17]=seg mass [18..32]=seg pos
// ---------------------------------------------------------------------------
__device__ __forceinline__ float wave_red(float v) {
    v += __shfl_xor(v, 32, 64);
    v += __shfl_xor(v, 16, 64);
    v += __shfl_xor(v, 8, 64);
    v += __shfl_xor(v, 4, 64);
    v += __shfl_xor(v, 2, 64);
    v += __shfl_xor(v, 1, 64);
    return v;
}

__global__ __launch_bounds__(256) void combine_kernel(const float* __restrict__ fwdD,
                                                      const float* __restrict__ bwdD,
                                                      const int* __restrict__ gbp, int ngb,
                                                      float* __restrict__ acc) {
    const int d = blockIdx.x;
    const int ofs = diag_off(d), imin = diag_imin(d), len = diag_len(d);
    const float dist = fwdD[TOTCELLS - 1];
    __shared__ float sseg[MAXSEG], ssegp[MAXSEG];
    __shared__ int sgb[MAXSEG + 1];
    const int tid = threadIdx.x;
    if (tid < MAXSEG) { sseg[tid] = 0.f; ssegp[tid] = 0.f; }
    if (tid < ngb && tid <= MAXSEG) sgb[tid] = gbp[tid];
    __syncthreads();

    float pT = 0.f, pTe = 0.f, pB = 0.f;
    const float invM1 = 1.f / (float)(MM - 1);
    const float invN1 = 1.f / (float)(NN - 1);
    const int nseg = ngb - 1;

    for (int x = tid; x < len; x += 256) {
        const int i0 = imin + x, j0 = d - i0;
        const float f = fwdD[ofs + x], b = bwdD[ofs + x];
        const float a = fexp2(-fmaxf(f + b - dist, 0.0f));
        const float jp = j0 * invN1, ip = i0 * invM1;
        pT += a;
        const float dt = ip - jp;
        pTe += a * dt * dt;
        int s = -1;
        for (int q = 0; q < nseg && q < MAXSEG; ++q)
            if (i0 >= sgb[q] && i0 < sgb[q + 1]) s = q;
        if (s >= 0) { atomicAdd(&sseg[s], a); atomicAdd(&ssegp[s], a * jp); }
        for (int q = 0; q < ngb && q <= MAXSEG; ++q) {
            const int bv = sgb[q];
            if (bv > 0 && bv < MM && i0 == bv) {
                const float dv = jp - (float)bv * invM1;
                pB += a * dv * dv;
            }
        }
    }
    pT = wave_red(pT); pTe = wave_red(pTe); pB = wave_red(pB);
    if ((tid & 63) == 0) {
        if (pT  != 0.f) atomicAdd(&acc[0], pT);
        if (pTe != 0.f) atomicAdd(&acc[1], pTe);
        if (pB  != 0.f) atomicAdd(&acc[2], pB);
    }
    __syncthreads();
    if (tid < nseg && tid < MAXSEG) {
        if (sseg[tid]  != 0.f) atomicAdd(&acc[3 + tid], sseg[tid]);
        if (ssegp[tid] != 0.f) atomicAdd(&acc[3 + MAXSEG + tid], ssegp[tid]);
    }
}

// ---------------------------------------------------------------------------
// Scalar epilogue replicating the reference's scale/order/coverage semantics.
// ---------------------------------------------------------------------------
__global__ void final_kernel(const float* __restrict__ acc,
                             const float* __restrict__ fwdD,
                             const int* __restrict__ gbp, int ngb,
                             float* __restrict__ out) {
    if (threadIdx.x != 0 || blockIdx.x != 0) return;
    const float dist = fwdD[TOTCELLS - 1] * UNSCALE;   // unscale shape loss
    const float Utot = acc[0];
    const float scale = (Utot > 1e-8f) ? ((float)(MM < NN ? MM : NN) / fmaxf(Utot, 1e-8f)) : 1.0f;
    const float temporal = scale * acc[1];

    int gb[MAXSEG + 1];
    const int n = (ngb <= MAXSEG + 1) ? ngb : (MAXSEG + 1);
    for (int q = 0; q < n; ++q) gb[q] = gbp[q];

    int nint = 0;
    for (int q = 0; q < n; ++q) if (gb[q] > 0 && gb[q] < MM) nint++;
    const float boundary = (nint > 0) ? (scale * acc[2] / (float)nint) : 0.f;

    float order = 0.f;
    if (n > 2) {
        float pos[MAXSEG];
        int np = 0;
        for (int s = 0; s + 1 < n; ++s) {
            const int st = gb[s], en = gb[s + 1];
            if (st >= MM || en > MM || st >= en) continue;
            const float mass = fmaxf(scale * acc[3 + s], 1e-8f);
            pos[np++] = scale * acc[3 + MAXSEG + s] / mass;
        }
        for (int k = 1; k < np; ++k) order += fmaxf(pos[k - 1] - pos[k], 0.f);
        if (np > 1) order /= (float)(np - 1);
    }

    float cov = 0.f;
    const int nsteps = n - 1;
    if (nsteps > 0) {
        for (int s = 0; s < nsteps; ++s) {
            const int st = gb[s];
            int en = gb[s + 1]; if (en > MM) en = MM;
            if (st >= en) continue;
            cov += fmaxf((float)(en - st) * 0.5f - scale * acc[3 + s], 0.f);
        }
        cov /= (float)nsteps;
    }

    out[0] = 0.3f * dist + 0.2f * temporal + 0.2f * boundary + 0.15f * order + 0.15f * cov;
}

// ---------------------------------------------------------------------------
extern "C" void kernel_launch(void* const* d_in, const int* in_sizes, int n_in,
                              void* d_out, int out_size, void* d_ws, size_t ws_size,
                              hipStream_t stream) {
    const float* pred   = (const float*)d_in[0];   // (2048, 64)
    const float* target = (const float*)d_in[1];   // (2048, 64)
    const int*   gb     = (const int*)d_in[2];     // (9,)
    const int ngb = in_sizes[2];

    float* costD = (float*)d_ws;
    float* fwdD  = costD + TOTCELLS;
    float* bwdD  = fwdD + TOTCELLS;
    float* acc   = bwdD + TOTCELLS;                 // 64 floats (zeroed by cost_kernel)
    unsigned* flagsP = (unsigned*)(acc + 64);       // [2][4] producer progress (zeroed)
    float* gringP    = (float*)(flagsP + 2 * NWGD); // [2][3][GRING]

    cost_kernel<<<dim3(NN / 64, MM / 64), 256, 0, stream>>>(pred, target, costD, acc);
    dp_pipe<<<2 * NWGD, NWAVE * 64, 0, stream>>>(costD, fwdD, bwdD, flagsP, gringP);
    combine_kernel<<<NDIAG, 256, 0, stream>>>(fwdD, bwdD, gb, ngb, acc);
    final_kernel<<<1, 64, 0, stream>>>(acc, fwdD, gb, ngb, (float*)d_out);
}

// Round 6
// 2056.750 us; speedup vs baseline: 2.3060x; 1.2726x over previous
//
#include <hip/hip_runtime.h>

#define MM 2048
#define NN 2048
#define DD 64
#define NDIAG (MM + NN - 1)      /* 4095 cost-matrix anti-diagonals */
#define TOTCELLS (MM * NN)
#define MAXSEG 15

// ---- skewed-pipeline DP geometry (identical to R5) ----
#define NWGD   4                 /* workgroups per direction               */
#define NWAVE  4                 /* waves per WG (1 strip per wave)        */
#define STRIPROWS 128            /* rows per strip (2 per lane)            */
#define KSTEP  32                /* steps per superstep (barrier cadence)  */
#define CPFD   4                 /* LDS->reg cost prefetch depth (steps)   */
#define EXTD   4                 /* LDS-ring prefetch distance (steps)     */
#define TSTEPS 4992              /* >= 4094 + Og(15)=888 + 1; 156*32       */
#define NSUPER (TSTEPS / KSTEP)
#define GRING  1024              /* global ring entries per WG boundary    */
#define LRING  256               /* LDS ring entries per strip boundary    */
// Strip g skew: Og = 40g + 96*(g/4); S_use(g) = Og + 128g = 168g + 96*(g/4).

constexpr float K2      = 14.426950408889634f;   // log2(e)/gamma, gamma=0.1
constexpr float INF_K   = 1.0e10f * 14.426950408889634f;
constexpr float UNSCALE = 0.06931471805599453f;  // gamma*ln2 = 1/K2

// Packed anti-diagonal layout for a 2048x2048 matrix: diag d = i+j, 0..4094.
__device__ __forceinline__ int diag_off(int d) {
    return (d < NN) ? ((d * (d + 1)) >> 1)
                    : (TOTCELLS - (((NDIAG - d) * (NDIAG - d + 1)) >> 1));
}
__device__ __forceinline__ int diag_imin(int d) { return (d < NN) ? 0 : (d - (NN - 1)); }
__device__ __forceinline__ int diag_len(int d)  { return (d < NN) ? (d + 1) : (NDIAG - d); }

__device__ __forceinline__ float fexp2(float x) { return __builtin_amdgcn_exp2f(x); }
__device__ __forceinline__ float flog2(float x) { return __builtin_amdgcn_logf(x); }

// rotate-up-by-1 across the wave via DPP wave_ror:1 (0x13C): lane l gets
// lane (l-1)&63's value at VALU latency. Lane 0's result is overridden.
__device__ __forceinline__ float rot_up1(float x) {
    int xi = __builtin_bit_cast(int, x);
    int r  = __builtin_amdgcn_update_dpp(xi, xi, 0x13C, 0xF, 0xF, true);
    return __builtin_bit_cast(float, r);
}

// softmin in the K2-scaled (log2) domain: m1 - log2(1 + 2^(m1-m2) + 2^(m1-m3))
__device__ __forceinline__ float softmin3k(float a, float b, float c) {
    const float m1 = fminf(fminf(a, b), c);
    const float m2 = __builtin_amdgcn_fmed3f(a, b, c);
    const float m3 = fmaxf(fmaxf(a, b), c);
    const float e  = 1.0f + fexp2(m1 - m2) + fexp2(m1 - m3);
    return m1 - flog2(e);
}

// ---------------------------------------------------------------------------
// cost[i,j] = K2 * sum_k (target[i,k]-pred[j,k])^2, packed diag layout.
// Block (0,0) also zeroes accumulators + pipeline flags (80 words).
// ---------------------------------------------------------------------------
__global__ __launch_bounds__(256) void cost_kernel(const float* __restrict__ pred,
                                                   const float* __restrict__ target,
                                                   float* __restrict__ costD,
                                                   float* __restrict__ acc) {
    __shared__ float Ts[64][65];
    __shared__ float Ps[64][65];
    const int tid = threadIdx.x;
    const int tx = tid & 15, ty = tid >> 4;
    const int i0 = blockIdx.y * 64;
    const int j0 = blockIdx.x * 64;

    if (blockIdx.x == 0 && blockIdx.y == 0 && tid < 80) ((unsigned*)acc)[tid] = 0u;

    #pragma unroll
    for (int rnd = 0; rnd < 4; ++rnd) {
        int f4i = tid + rnd * 256;
        int r  = f4i >> 4;
        int k4 = (f4i & 15) << 2;
        float4 tv = *reinterpret_cast<const float4*>(target + (size_t)(i0 + r) * DD + k4);
        Ts[r][k4 + 0] = tv.x; Ts[r][k4 + 1] = tv.y; Ts[r][k4 + 2] = tv.z; Ts[r][k4 + 3] = tv.w;
        float4 pv = *reinterpret_cast<const float4*>(pred + (size_t)(j0 + r) * DD + k4);
        Ps[k4 + 0][r] = pv.x; Ps[k4 + 1][r] = pv.y; Ps[k4 + 2][r] = pv.z; Ps[k4 + 3][r] = pv.w;
    }
    __syncthreads();

    float accv[4][4];
    #pragma unroll
    for (int a = 0; a < 4; ++a)
        #pragma unroll
        for (int b = 0; b < 4; ++b) accv[a][b] = 0.f;

    for (int k = 0; k < 64; ++k) {
        float ta[4], pb[4];
        #pragma unroll
        for (int a = 0; a < 4; ++a) ta[a] = Ts[ty + 16 * a][k];
        #pragma unroll
        for (int b = 0; b < 4; ++b) pb[b] = Ps[k][tx + 16 * b];
        #pragma unroll
        for (int a = 0; a < 4; ++a)
            #pragma unroll
            for (int b = 0; b < 4; ++b) {
                float d = ta[a] - pb[b];
                accv[a][b] = fmaf(d, d, accv[a][b]);
            }
    }
    #pragma unroll
    for (int a = 0; a < 4; ++a) {
        int i = i0 + ty + 16 * a;
        #pragma unroll
        for (int b = 0; b < 4; ++b) {
            int j = j0 + tx + 16 * b;
            int d = i + j;
            costD[diag_off(d) + (i - diag_imin(d))] = accv[a][b] * K2;
        }
    }
}

// ---------------------------------------------------------------------------
// Skewed register-resident soft-DTW, cost staged through LDS.
// blocks 0-3: forward -> fwdD. blocks 4-7: backward on the 180-rotated cost
// -> bwdD (identity flat_orig = TOTCELLS-1-flat_rot handled purely in the
// staging source addresses; LDS layout is rot-linear for both directions).
// Per superstep each wave issues 64 global_load_lds(4B) staging the NEXT
// superstep's 32 diagonals x 128 rows; the step loop does ZERO global loads
// (cost comes from LDS via a 4-deep ds_read_b64 register ring on lgkmcnt),
// so the only vmcnt wait is the once-per-superstep barrier drain.
// ---------------------------------------------------------------------------
__global__ __launch_bounds__(256) void dp_pipe(const float* __restrict__ costD,
                                               float* __restrict__ fwdD,
                                               float* __restrict__ bwdD,
                                               unsigned* __restrict__ flagsP,
                                               float* __restrict__ gringP) {
    __shared__ float cls[2][NWAVE][KSTEP][STRIPROWS];   // 128 KB cost staging
    __shared__ float ring[NWAVE + 1][LRING];            // 5 KB boundary rings
    const int dir  = (int)blockIdx.x >> 2;
    const int wg   = (int)blockIdx.x & 3;
    const int tid  = threadIdx.x;
    const int wv   = tid >> 6;
    const int lane = tid & 63;
    const int g    = wg * NWAVE + wv;
    const int gu   = __builtin_amdgcn_readfirstlane(g);
    const int Og   = __builtin_amdgcn_readfirstlane(40 * g + 96 * (g >> 2));
    const int Suse = __builtin_amdgcn_readfirstlane(168 * g + 96 * (g >> 2));
    const int r0   = STRIPROWS * g + 2 * lane;
    float* __restrict__ outD = dir ? bwdD : fwdD;
    unsigned* pf = flagsP + dir * NWGD;
    float* grd   = gringP + (size_t)dir * 3 * GRING;
    const float* mring = ring[(wv == 0) ? NWAVE : (wv - 1)];
    const int sgn = dir ? -1 : 1;

    // incremental per-lane output address: aS tracks diag dd
    int aS;
    {
        const int b0 = r0;                        // flat_rot at dd=0
        aS = dir ? (TOTCELLS - 1 - b0) : b0;
    }

    // Stage 32 slices (diags tb-Og .. tb-Og+31, rows 128g..128g+127) into
    // cls[bsel]. LDS dest is wave-uniform base + lane*4 (linear, rot order);
    // the dir-1 reversal lives entirely in the per-lane GLOBAL src address.
    auto STAGE = [&](int tb, int bsel) {
        #pragma unroll 8
        for (int j = 0; j < 64; ++j) {
            const int s  = j >> 1;
            const int e0 = (j & 1) << 6;          // 0 or 64
            const int dd = tb + s - Og;           // may be out of range
            const int ddc = (dd < 0) ? 0 : ((dd > NDIAG - 1) ? NDIAG - 1 : dd);
            const int rb  = diag_off(ddc) - diag_imin(ddc) + STRIPROWS * gu;
            int src = rb + e0 + lane;             // rot-flat of rot row e
            if (dir) src = (TOTCELLS - 1) - src;  // packed-layout rotation
            src = (src < 0) ? 0 : ((src > TOTCELLS - 1) ? (TOTCELLS - 1) : src);
            __builtin_amdgcn_global_load_lds(
                (const __attribute__((address_space(1))) void*)(costD + src),
                (__attribute__((address_space(3))) void*)&cls[bsel][wv][s][e0],
                4, 0, 0);
        }
    };

    float Rk0 = INF_K, Rk0m1 = INF_K, Rk1 = INF_K;
    float dg0 = (g == 0 && lane == 0) ? 0.0f : INF_K;  // virtual R[0,0]=0
    float ext[8];
    #pragma unroll
    for (int z = 0; z < 8; ++z) ext[z] = INF_K;

    // prologue: stage buffer 0 (diags -Og .. -Og+31), then make it visible
    STAGE(0, 0);
    __syncthreads();

    for (unsigned m = 0; m < NSUPER; ++m) {
        const int tbase = (int)(m * KSTEP);
        const int bsel  = (int)(m & 1);

        // ---- inter-WG gather (wv0, wg>0): columns [c0g, c0g+63] -> ring[4]
        if (wv == 0 && wg > 0) {
            const int c0g = tbase - Suse;
            if (c0g + 63 >= 0 && c0g < NN) {
                const unsigned need = m - 1;
                unsigned guard = 0;
                while (__hip_atomic_load(&pf[wg - 1], __ATOMIC_ACQUIRE,
                                         __HIP_MEMORY_SCOPE_AGENT) < need &&
                       guard < (1u << 20)) { __builtin_amdgcn_s_sleep(8); ++guard; }
                const int c = c0g + lane;
                if (c >= 0 && c < NN)
                    ring[NWAVE][c & (LRING - 1)] =
                        __hip_atomic_load(&grd[(wg - 1) * GRING + (c & (GRING - 1))],
                                          __ATOMIC_RELAXED, __HIP_MEMORY_SCOPE_AGENT);
            }
        }

        // ---- issue staging for the NEXT superstep (drained at the barrier)
        if (m + 1 < NSUPER) STAGE(tbase + KSTEP, bsel ^ 1);

        // ---- LDS->reg cost prologue: slots for q = 0..3
        float2 ccr[CPFD];
        #pragma unroll
        for (int p = 0; p < CPFD; ++p)
            ccr[p] = *reinterpret_cast<const float2*>(&cls[bsel][wv][p][2 * lane]);

        // ---- 32 wavefront steps (four 8-unrolled groups; slots static)
        for (int tu = 0; tu < KSTEP; tu += 8) {
            #pragma unroll
            for (int q8 = 0; q8 < 8; ++q8) {
                const int q  = tu + q8;
                const int t  = tbase + q;
                const int dd = t - Og;             // wave-uniform
                // consume cost slot (ds_read issued CPFD steps ago), then refill
                const float uc0 = ccr[q8 & 3].x;
                const float uc1 = ccr[q8 & 3].y;
                if (q < KSTEP - CPFD)
                    ccr[q8 & 3] = *reinterpret_cast<const float2*>(
                        &cls[bsel][wv][q + CPFD][2 * lane]);
                if (dd >= 0 && dd < NDIAG) {
                    const int ec = t - Suse;       // boundary column this step
                    float extv = INF_K;
                    if (g != 0 && ec >= 0 && ec < NN) extv = ext[q8];
                    if (g != 0)                    // prefetch ring value for t+EXTD
                        ext[(q8 + EXTD) & 7] =
                            mring[((unsigned)(t + EXTD - Suse)) & (LRING - 1)];
                    const float shr = rot_up1(Rk1);          // neighbor row r0-1
                    const float up0 = (lane == 0) ? extv : shr;
                    const float n0 = uc0 + softmin3k(dg0, up0, Rk0);
                    const float n1 = uc1 + softmin3k(Rk0m1, Rk0, Rk1);
                    const int c0 = dd - r0;
                    const bool v0 = (c0 >= 0) && (c0 < NN);
                    const bool v1 = (c0 >= 1) && (c0 <= NN);
                    Rk0m1 = Rk0;
                    if (v0) Rk0 = n0;
                    if (v1) Rk1 = n1;
                    dg0 = up0;
                    if (v0) outD[aS] = Rk0;
                    if (v1) outD[aS + sgn] = Rk1;
                    const int pc = ec - (STRIPROWS - 1);   // publish last row
                    if (lane == 63 && pc >= 0 && pc < NN)
                        ring[wv][pc & (LRING - 1)] = Rk1;
                    const int ds = (dd + 1 < NDIAG - 1 - dd) ? (dd + 1) : (NDIAG - 1 - dd);
                    aS += sgn * ds;
                }
            }
        }
        __syncthreads();

        // ---- inter-WG flush (wv0): ring[3] -> global ring, then flag
        if (wv == 0 && wg < NWGD - 1) {
            const int Sp = 768 * wg + 504;          // S_use of strip 4wg+3
            const int cb = tbase - Sp - (STRIPROWS - 1);
            if (lane < KSTEP) {
                const int c = cb + lane;
                if (c >= 0 && c < NN)
                    __hip_atomic_store(&grd[wg * GRING + (c & (GRING - 1))],
                                       ring[NWAVE - 1][c & (LRING - 1)],
                                       __ATOMIC_RELAXED, __HIP_MEMORY_SCOPE_AGENT);
            }
            if (lane == 0)
                __hip_atomic_store(&pf[wg], m + 1, __ATOMIC_RELEASE,
                                   __HIP_MEMORY_SCOPE_AGENT);
        }
    }
}

// ---------------------------------------------------------------------------
// Per-cell alignment + linear reductions. a = exp2(-max(f + B - dist, 0)).
// acc: [0]=total [1]=temporal [2]=boundary [3..17]=seg mass [18..32]=seg pos
// ---------------------------------------------------------------------------
__device__ __forceinline__ float wave_red(float v) {
    v += __shfl_xor(v, 32, 64);
    v += __shfl_xor(v, 16, 64);
    v += __shfl_xor(v, 8, 64);
    v += __shfl_xor(v, 4, 64);
    v += __shfl_xor(v, 2, 64);
    v += __shfl_xor(v, 1, 64);
    return v;
}

__global__ __launch_bounds__(256) void combine_kernel(const float* __restrict__ fwdD,
                                                      const float* __restrict__ bwdD,
                                                      const int* __restrict__ gbp, int ngb,
                                                      float* __restrict__ acc) {
    const int d = blockIdx.x;
    const int ofs = diag_off(d), imin = diag_imin(d), len = diag_len(d);
    const float dist = fwdD[TOTCELLS - 1];
    __shared__ float sseg[MAXSEG], ssegp[MAXSEG];
    __shared__ int sgb[MAXSEG + 1];
    const int tid = threadIdx.x;
    if (tid < MAXSEG) { sseg[tid] = 0.f; ssegp[tid] = 0.f; }
    if (tid < ngb && tid <= MAXSEG) sgb[tid] = gbp[tid];
    __syncthreads();

    float pT = 0.f, pTe = 0.f, pB = 0.f;
    const float invM1 = 1.f / (float)(MM - 1);
    const float invN1 = 1.f / (float)(NN - 1);
    const int nseg = ngb - 1;

    for (int x = tid; x < len; x += 256) {
        const int i0 = imin + x, j0 = d - i0;
        const float f = fwdD[ofs + x], b = bwdD[ofs + x];
        const float a = fexp2(-fmaxf(f + b - dist, 0.0f));
        const float jp = j0 * invN1, ip = i0 * invM1;
        pT += a;
        const float dt = ip - jp;
        pTe += a * dt * dt;
        int s = -1;
        for (int q = 0; q < nseg && q < MAXSEG; ++q)
            if (i0 >= sgb[q] && i0 < sgb[q + 1]) s = q;
        if (s >= 0) { atomicAdd(&sseg[s], a); atomicAdd(&ssegp[s], a * jp); }
        for (int q = 0; q < ngb && q <= MAXSEG; ++q) {
            const int bv = sgb[q];
            if (bv > 0 && bv < MM && i0 == bv) {
                const float dv = jp - (float)bv * invM1;
                pB += a * dv * dv;
            }
        }
    }
    pT = wave_red(pT); pTe = wave_red(pTe); pB = wave_red(pB);
    if ((tid & 63) == 0) {
        if (pT  != 0.f) atomicAdd(&acc[0], pT);
        if (pTe != 0.f) atomicAdd(&acc[1], pTe);
        if (pB  != 0.f) atomicAdd(&acc[2], pB);
    }
    __syncthreads();
    if (tid < nseg && tid < MAXSEG) {
        if (sseg[tid]  != 0.f) atomicAdd(&acc[3 + tid], sseg[tid]);
        if (ssegp[tid] != 0.f) atomicAdd(&acc[3 + MAXSEG + tid], ssegp[tid]);
    }
}

// ---------------------------------------------------------------------------
// Scalar epilogue replicating the reference's scale/order/coverage semantics.
// ---------------------------------------------------------------------------
__global__ void final_kernel(const float* __restrict__ acc,
                             const float* __restrict__ fwdD,
                             const int* __restrict__ gbp, int ngb,
                             float* __restrict__ out) {
    if (threadIdx.x != 0 || blockIdx.x != 0) return;
    const float dist = fwdD[TOTCELLS - 1] * UNSCALE;   // unscale shape loss
    const float Utot = acc[0];
    const float scale = (Utot > 1e-8f) ? ((float)(MM < NN ? MM : NN) / fmaxf(Utot, 1e-8f)) : 1.0f;
    const float temporal = scale * acc[1];

    int gb[MAXSEG + 1];
    const int n = (ngb <= MAXSEG + 1) ? ngb : (MAXSEG + 1);
    for (int q = 0; q < n; ++q) gb[q] = gbp[q];

    int nint = 0;
    for (int q = 0; q < n; ++q) if (gb[q] > 0 && gb[q] < MM) nint++;
    const float boundary = (nint > 0) ? (scale * acc[2] / (float)nint) : 0.f;

    float order = 0.f;
    if (n > 2) {
        float pos[MAXSEG];
        int np = 0;
        for (int s = 0; s + 1 < n; ++s) {
            const int st = gb[s], en = gb[s + 1];
            if (st >= MM || en > MM || st >= en) continue;
            const float mass = fmaxf(scale * acc[3 + s], 1e-8f);
            pos[np++] = scale * acc[3 + MAXSEG + s] / mass;
        }
        for (int k = 1; k < np; ++k) order += fmaxf(pos[k - 1] - pos[k], 0.f);
        if (np > 1) order /= (float)(np - 1);
    }

    float cov = 0.f;
    const int nsteps = n - 1;
    if (nsteps > 0) {
        for (int s = 0; s < nsteps; ++s) {
            const int st = gb[s];
            int en = gb[s + 1]; if (en > MM) en = MM;
            if (st >= en) continue;
            cov += fmaxf((float)(en - st) * 0.5f - scale * acc[3 + s], 0.f);
        }
        cov /= (float)nsteps;
    }

    out[0] = 0.3f * dist + 0.2f * temporal + 0.2f * boundary + 0.15f * order + 0.15f * cov;
}

// ---------------------------------------------------------------------------
extern "C" void kernel_launch(void* const* d_in, const int* in_sizes, int n_in,
                              void* d_out, int out_size, void* d_ws, size_t ws_size,
                              hipStream_t stream) {
    const float* pred   = (const float*)d_in[0];   // (2048, 64)
    const float* target = (const float*)d_in[1];   // (2048, 64)
    const int*   gb     = (const int*)d_in[2];     // (9,)
    const int ngb = in_sizes[2];

    float* costD = (float*)d_ws;
    float* fwdD  = costD + TOTCELLS;
    float* bwdD  = fwdD + TOTCELLS;
    float* acc   = bwdD + TOTCELLS;                 // 64 floats (zeroed by cost_kernel)
    unsigned* flagsP = (unsigned*)(acc + 64);       // [2][4] producer progress (zeroed)
    float* gringP    = (float*)(flagsP + 2 * NWGD); // [2][3][GRING]

    cost_kernel<<<dim3(NN / 64, MM / 64), 256, 0, stream>>>(pred, target, costD, acc);
    dp_pipe<<<2 * NWGD, NWAVE * 64, 0, stream>>>(costD, fwdD, bwdD, flagsP, gringP);
    combine_kernel<<<NDIAG, 256, 0, stream>>>(fwdD, bwdD, gb, ngb, acc);
    final_kernel<<<1, 64, 0, stream>>>(acc, fwdD, gb, ngb, (float*)d_out);
}